// Round 1
// baseline (3091.253 us; speedup 1.0000x reference)
//
#include <hip/hip_runtime.h>

#define NG 64   // graphs

// ---------------- histogram (int atomics) ----------------
__global__ void hist_kernel(const int* __restrict__ idx, int n, int* __restrict__ cnt) {
    int i = blockIdx.x * blockDim.x + threadIdx.x;
    int stride = gridDim.x * blockDim.x;
    for (; i < n; i += stride) atomicAdd(&cnt[idx[i]], 1);
}

// ---------------- 3-way exclusive scan -> row_ptr ----------------
__global__ __launch_bounds__(1024) void scan3_kernel(
    const int* __restrict__ c0, int* __restrict__ r0,
    const int* __restrict__ c1, int* __restrict__ r1,
    const int* __restrict__ c2, int* __restrict__ r2, int N)
{
    const int* c = blockIdx.x == 0 ? c0 : (blockIdx.x == 1 ? c1 : c2);
    int*       r = blockIdx.x == 0 ? r0 : (blockIdx.x == 1 ? r1 : r2);
    __shared__ int s[1024];
    __shared__ int carry;
    int t = threadIdx.x;
    if (t == 0) { carry = 0; r[0] = 0; }
    __syncthreads();
    for (int base = 0; base < N; base += 1024) {
        int i = base + t;
        int v = (i < N) ? c[i] : 0;
        s[t] = v;
        __syncthreads();
        for (int off = 1; off < 1024; off <<= 1) {
            int u = (t >= off) ? s[t - off] : 0;
            __syncthreads();
            s[t] += u;
            __syncthreads();
        }
        int incl = s[t];
        int tot  = s[1023];
        int cbase = carry;
        if (i < N) r[i + 1] = cbase + incl;
        __syncthreads();
        if (t == 0) carry = cbase + tot;
        __syncthreads();
    }
}

// ---------------- CSR fill ----------------
__global__ void fill_kernel(const int* __restrict__ src, const int* __restrict__ dst, int E,
                            const int* __restrict__ rp, int* __restrict__ cur, int* __restrict__ csr)
{
    int i = blockIdx.x * blockDim.x + threadIdx.x;
    int stride = gridDim.x * blockDim.x;
    for (; i < E; i += stride) {
        int d = dst[i];
        int pos = rp[d] + atomicAdd(&cur[d], 1);
        csr[pos] = src[i];
    }
}

// ---------------- elementwise add (weight/bias sums) ----------------
__global__ void add2_kernel(const float* __restrict__ a, const float* __restrict__ b,
                            float* __restrict__ o, int n) {
    int i = blockIdx.x * blockDim.x + threadIdx.x;
    if (i < n) o[i] = a[i] + b[i];
}

// ---------------- fused (CSR-mean | dense) x [128x128] GEMM ----------------
// C[M,128] (+)= A(or mean-aggregated rows) @ W, optional bias/relu.
template<bool CSRMEAN, bool ACC, bool BIAS, bool RELU>
__global__ __launch_bounds__(256, 2) void gemm_kernel(
    const float* __restrict__ A, int M,
    const float* __restrict__ xsrc,
    const int* __restrict__ rp, const int* __restrict__ csr,
    const float* __restrict__ W, const float* __restrict__ bias,
    float* __restrict__ C)
{
    __shared__ float Ws[128 * 128];   // 64 KB
    __shared__ float As[32 * 128];    // 16 KB  (total 80 KB -> 2 blocks/CU)
    const int t = threadIdx.x;
    const int row0 = blockIdx.x * 32;

    // W -> LDS (4096 float4)
    {
        const float4* wg = (const float4*)W;
        float4* wl = (float4*)Ws;
        #pragma unroll
        for (int i = 0; i < 16; ++i) wl[t + 256 * i] = wg[t + 256 * i];
    }
    // A tile -> LDS
    if (!CSRMEAN) {
        #pragma unroll
        for (int i = 0; i < 4; ++i) {
            int f = t + 256 * i;          // 0..1023 float4 within tile
            int rr = f >> 5, cv = f & 31;
            int rg = row0 + rr;
            float4 v = make_float4(0.f, 0.f, 0.f, 0.f);
            if (rg < M) v = ((const float4*)A)[rg * 32 + cv];
            *((float4*)&As[rr * 128 + cv * 4]) = v;
        }
    } else {
        int wave = t >> 6, lane = t & 63;
        for (int rr = wave * 8; rr < wave * 8 + 8; ++rr) {
            int rg = row0 + rr;
            float ax = 0.f, ay = 0.f;
            if (rg < M) {
                int s0 = rp[rg], s1 = rp[rg + 1];
                int j = s0;
                for (; j + 4 <= s1; j += 4) {
                    int i0 = csr[j], i1 = csr[j + 1], i2 = csr[j + 2], i3 = csr[j + 3];
                    float2 v0 = *(const float2*)&xsrc[i0 * 128 + lane * 2];
                    float2 v1 = *(const float2*)&xsrc[i1 * 128 + lane * 2];
                    float2 v2 = *(const float2*)&xsrc[i2 * 128 + lane * 2];
                    float2 v3 = *(const float2*)&xsrc[i3 * 128 + lane * 2];
                    ax += (v0.x + v1.x) + (v2.x + v3.x);
                    ay += (v0.y + v1.y) + (v2.y + v3.y);
                }
                for (; j < s1; ++j) {
                    float2 v = *(const float2*)&xsrc[csr[j] * 128 + lane * 2];
                    ax += v.x; ay += v.y;
                }
                int deg = s1 - s0;
                float sc = 1.f / (float)(deg > 1 ? deg : 1);
                ax *= sc; ay *= sc;
            }
            float2 o2; o2.x = ax; o2.y = ay;
            *((float2*)&As[rr * 128 + lane * 2]) = o2;
        }
    }
    __syncthreads();

    const int tx = t & 31, ty = t >> 5;     // tx: col group, ty: row group (0..7)
    float acc[4][4];
    #pragma unroll
    for (int i = 0; i < 4; ++i) { acc[i][0] = 0.f; acc[i][1] = 0.f; acc[i][2] = 0.f; acc[i][3] = 0.f; }

    #pragma unroll 8
    for (int k = 0; k < 128; ++k) {
        float4 w4 = *((const float4*)&Ws[k * 128 + tx * 4]);
        #pragma unroll
        for (int i = 0; i < 4; ++i) {
            float a = As[(ty * 4 + i) * 128 + k];
            acc[i][0] += a * w4.x;
            acc[i][1] += a * w4.y;
            acc[i][2] += a * w4.z;
            acc[i][3] += a * w4.w;
        }
    }

    float4 bv = make_float4(0.f, 0.f, 0.f, 0.f);
    if (BIAS) bv = *((const float4*)&bias[tx * 4]);
    #pragma unroll
    for (int i = 0; i < 4; ++i) {
        int rg = row0 + ty * 4 + i;
        if (rg >= M) continue;
        float4 res;
        res.x = acc[i][0]; res.y = acc[i][1]; res.z = acc[i][2]; res.w = acc[i][3];
        if (BIAS) { res.x += bv.x; res.y += bv.y; res.z += bv.z; res.w += bv.w; }
        if (ACC) {
            float4 cc = ((const float4*)C)[rg * 32 + tx];
            res.x += cc.x; res.y += cc.y; res.z += cc.z; res.w += cc.w;
        }
        if (RELU) {
            res.x = fmaxf(res.x, 0.f); res.y = fmaxf(res.y, 0.f);
            res.z = fmaxf(res.z, 0.f); res.w = fmaxf(res.w, 0.f);
        }
        ((float4*)C)[rg * 32 + tx] = res;
    }
}

// ---------------- layer-2: per-row CSR mean, pooled per graph ----------------
__global__ void aggpool_kernel(const float* __restrict__ xsrc,
                               const int* __restrict__ rp, const int* __restrict__ csr,
                               const int* __restrict__ batch, int M,
                               float* __restrict__ pool /* [64][128] */)
{
    int wave = threadIdx.x >> 6, lane = threadIdx.x & 63;
    int row = blockIdx.x * 4 + wave;
    if (row >= M) return;
    int s0 = rp[row], s1 = rp[row + 1];
    float ax = 0.f, ay = 0.f;
    int j = s0;
    for (; j + 4 <= s1; j += 4) {
        int i0 = csr[j], i1 = csr[j + 1], i2 = csr[j + 2], i3 = csr[j + 3];
        float2 v0 = *(const float2*)&xsrc[i0 * 128 + lane * 2];
        float2 v1 = *(const float2*)&xsrc[i1 * 128 + lane * 2];
        float2 v2 = *(const float2*)&xsrc[i2 * 128 + lane * 2];
        float2 v3 = *(const float2*)&xsrc[i3 * 128 + lane * 2];
        ax += (v0.x + v1.x) + (v2.x + v3.x);
        ay += (v0.y + v1.y) + (v2.y + v3.y);
    }
    for (; j < s1; ++j) {
        float2 v = *(const float2*)&xsrc[csr[j] * 128 + lane * 2];
        ax += v.x; ay += v.y;
    }
    int deg = s1 - s0;
    float sc = 1.f / (float)(deg > 1 ? deg : 1);
    int g = batch[row];
    atomicAdd(&pool[g * 128 + lane * 2],     ax * sc);
    atomicAdd(&pool[g * 128 + lane * 2 + 1], ay * sc);
}

// ---------------- sum rows of x by batch -> pool[64][128] ----------------
__global__ void rowpool_kernel(const float* __restrict__ x, const int* __restrict__ batch,
                               int M, float* __restrict__ pool)
{
    int i = blockIdx.x * blockDim.x + threadIdx.x;  // float4 index
    int total = M * 32;
    int stride = gridDim.x * blockDim.x;
    for (; i < total; i += stride) {
        int rr = i >> 5, cv = i & 31;
        float4 v = ((const float4*)x)[i];
        int g = batch[rr];
        atomicAdd(&pool[g * 128 + cv * 4 + 0], v.x);
        atomicAdd(&pool[g * 128 + cv * 4 + 1], v.y);
        atomicAdd(&pool[g * 128 + cv * 4 + 2], v.z);
        atomicAdd(&pool[g * 128 + cv * 4 + 3], v.w);
    }
}

// ---------------- final: layer-2 matmuls at graph level + MLP + log_softmax ----------------
__global__ __launch_bounds__(128) void final_kernel(
    const float* __restrict__ pmdu, const float* __restrict__ pmuu, const float* __restrict__ pmud,
    const float* __restrict__ pu1,  const float* __restrict__ pd1,
    const int* __restrict__ cgu, const int* __restrict__ cgd,
    const float* __restrict__ Wl2_du, const float* __restrict__ bl2_du, const float* __restrict__ Wr2_du,
    const float* __restrict__ Wl2_uu, const float* __restrict__ bl2_uu, const float* __restrict__ Wr2_uu,
    const float* __restrict__ Wl2_ud, const float* __restrict__ bl2_ud, const float* __restrict__ Wr2_ud,
    const float* __restrict__ W1, const float* __restrict__ b1,
    const float* __restrict__ W2, const float* __restrict__ b2,
    float* __restrict__ out)
{
    int g = blockIdx.x, t = threadIdx.x;   // 128 threads
    __shared__ float smdu[128], smuu[128], smud[128], su1[128], sd1[128];
    __shared__ float xrow[256], h[128], lg[2];
    smdu[t] = pmdu[g * 128 + t];
    smuu[t] = pmuu[g * 128 + t];
    smud[t] = pmud[g * 128 + t];
    su1[t]  = pu1[g * 128 + t];
    sd1[t]  = pd1[g * 128 + t];
    __syncthreads();
    float ncu = (float)cgu[g], ncd = (float)cgd[g];
    float cu = ncu > 1.f ? ncu : 1.f, cd = ncd > 1.f ? ncd : 1.f;
    // u2/d2 pooled sums (pool commutes with linear layer-2), col t
    float accu = ncu * (bl2_du[t] + bl2_uu[t]);
    float accd = ncd * bl2_ud[t];
    for (int k = 0; k < 128; ++k) {
        accu += smdu[k] * Wl2_du[k * 128 + t]
              + smuu[k] * Wl2_uu[k * 128 + t]
              + su1[k]  * (Wr2_du[k * 128 + t] + Wr2_uu[k * 128 + t]);
        accd += smud[k] * Wl2_ud[k * 128 + t]
              + sd1[k]  * Wr2_ud[k * 128 + t];
    }
    xrow[t]       = accu / cu;
    xrow[128 + t] = accd / cd;
    __syncthreads();
    float hh = b1[t];
    for (int k = 0; k < 256; ++k) hh += xrow[k] * W1[k * 128 + t];
    h[t] = fmaxf(hh, 0.f);
    __syncthreads();
    if (t < 2) {
        float l = b2[t];
        for (int k = 0; k < 128; ++k) l += h[k] * W2[k * 2 + t];
        lg[t] = l;
    }
    __syncthreads();
    if (t == 0) {
        float m = fmaxf(lg[0], lg[1]);
        float lse = m + logf(expf(lg[0] - m) + expf(lg[1] - m));
        out[g * 2 + 0] = lg[0] - lse;
        out[g * 2 + 1] = lg[1] - lse;
    }
}

extern "C" void kernel_launch(void* const* d_in, const int* in_sizes, int n_in,
                              void* d_out, int out_size, void* d_ws, size_t ws_size,
                              hipStream_t stream)
{
    const float* x_user = (const float*)d_in[0];
    const float* x_drug = (const float*)d_in[1];
    const int* ei_ud = (const int*)d_in[2];
    const int* ei_du = (const int*)d_in[3];
    const int* ei_uu = (const int*)d_in[4];
    const int* batch_u = (const int*)d_in[5];
    const int* batch_d = (const int*)d_in[6];
    const float* Wl1_ud = (const float*)d_in[7];  const float* bl1_ud = (const float*)d_in[8];  const float* Wr1_ud = (const float*)d_in[9];
    const float* Wl1_du = (const float*)d_in[10]; const float* bl1_du = (const float*)d_in[11]; const float* Wr1_du = (const float*)d_in[12];
    const float* Wl1_uu = (const float*)d_in[13]; const float* bl1_uu = (const float*)d_in[14]; const float* Wr1_uu = (const float*)d_in[15];
    const float* Wl2_ud = (const float*)d_in[16]; const float* bl2_ud = (const float*)d_in[17]; const float* Wr2_ud = (const float*)d_in[18];
    const float* Wl2_du = (const float*)d_in[19]; const float* bl2_du = (const float*)d_in[20]; const float* Wr2_du = (const float*)d_in[21];
    const float* Wl2_uu = (const float*)d_in[22]; const float* bl2_uu = (const float*)d_in[23]; const float* Wr2_uu = (const float*)d_in[24];
    const float* W1 = (const float*)d_in[25]; const float* b1 = (const float*)d_in[26];
    const float* W2 = (const float*)d_in[27]; const float* b2 = (const float*)d_in[28];
    (void)n_in; (void)out_size; (void)ws_size;

    const int N = in_sizes[0] / 128;
    const int E = in_sizes[2] / 2;

    char* ws = (char*)d_ws;
    size_t off = 0;
    auto alloc = [&](size_t bytes) -> void* {
        void* p = ws + off;
        off = (off + bytes + 255) & ~(size_t)255;
        return p;
    };
    int* csr_ud = (int*)alloc((size_t)E * 4);
    int* csr_du = (int*)alloc((size_t)E * 4);
    int* csr_uu = (int*)alloc((size_t)E * 4);
    int* rp_ud = (int*)alloc((size_t)(N + 1) * 4);
    int* rp_du = (int*)alloc((size_t)(N + 1) * 4);
    int* rp_uu = (int*)alloc((size_t)(N + 1) * 4);
    int* cnt_ud = (int*)alloc((size_t)N * 4);
    int* cnt_du = (int*)alloc((size_t)N * 4);
    int* cnt_uu = (int*)alloc((size_t)N * 4);
    float* u1 = (float*)alloc((size_t)N * 128 * 4);
    float* d1 = (float*)alloc((size_t)N * 128 * 4);
    float* pmdu = (float*)alloc(NG * 128 * 4);
    float* pmuu = (float*)alloc(NG * 128 * 4);
    float* pmud = (float*)alloc(NG * 128 * 4);
    float* pu1  = (float*)alloc(NG * 128 * 4);
    float* pd1  = (float*)alloc(NG * 128 * 4);
    int* cgu = (int*)alloc(NG * 4);
    int* cgd = (int*)alloc(NG * 4);
    float* Wr1s_u = (float*)alloc(128 * 128 * 4);
    float* b1s_u  = (float*)alloc(128 * 4);

    const int* dst_ud = ei_ud + E;
    const int* dst_du = ei_du + E;
    const int* dst_uu = ei_uu + E;

    // ---- CSR build (reused by both layers) ----
    hipMemsetAsync(cnt_ud, 0, (size_t)N * 4, stream);
    hipMemsetAsync(cnt_du, 0, (size_t)N * 4, stream);
    hipMemsetAsync(cnt_uu, 0, (size_t)N * 4, stream);
    hist_kernel<<<2048, 256, 0, stream>>>(dst_ud, E, cnt_ud);
    hist_kernel<<<2048, 256, 0, stream>>>(dst_du, E, cnt_du);
    hist_kernel<<<2048, 256, 0, stream>>>(dst_uu, E, cnt_uu);
    scan3_kernel<<<3, 1024, 0, stream>>>(cnt_ud, rp_ud, cnt_du, rp_du, cnt_uu, rp_uu, N);
    hipMemsetAsync(cnt_ud, 0, (size_t)N * 4, stream);
    hipMemsetAsync(cnt_du, 0, (size_t)N * 4, stream);
    hipMemsetAsync(cnt_uu, 0, (size_t)N * 4, stream);
    fill_kernel<<<2048, 256, 0, stream>>>(ei_ud, dst_ud, E, rp_ud, cnt_ud, csr_ud);
    fill_kernel<<<2048, 256, 0, stream>>>(ei_du, dst_du, E, rp_du, cnt_du, csr_du);
    fill_kernel<<<2048, 256, 0, stream>>>(ei_uu, dst_uu, E, rp_uu, cnt_uu, csr_uu);

    // ---- weight/bias sums for the doubled root term on user nodes ----
    add2_kernel<<<64, 256, 0, stream>>>(Wr1_du, Wr1_uu, Wr1s_u, 128 * 128);
    add2_kernel<<<1, 128, 0, stream>>>(bl1_du, bl1_uu, b1s_u, 128);

    // ---- layer 1 (full-size, fused CSR-mean GEMMs) ----
    int gB = (N + 31) / 32;
    gemm_kernel<false, false, true,  false><<<gB, 256, 0, stream>>>(x_user, N, nullptr, nullptr, nullptr, Wr1s_u, b1s_u, u1);
    gemm_kernel<true,  true,  false, false><<<gB, 256, 0, stream>>>(nullptr, N, x_drug, rp_du, csr_du, Wl1_du, nullptr, u1);
    gemm_kernel<true,  true,  false, true ><<<gB, 256, 0, stream>>>(nullptr, N, x_user, rp_uu, csr_uu, Wl1_uu, nullptr, u1);
    gemm_kernel<false, false, true,  false><<<gB, 256, 0, stream>>>(x_drug, N, nullptr, nullptr, nullptr, Wr1_ud, bl1_ud, d1);
    gemm_kernel<true,  true,  false, true ><<<gB, 256, 0, stream>>>(nullptr, N, x_user, rp_ud, csr_ud, Wl1_ud, nullptr, d1);

    // ---- layer 2: pooling commutes with the linear layer -> pool first ----
    hipMemsetAsync(pmdu, 0, NG * 128 * 4, stream);
    hipMemsetAsync(pmuu, 0, NG * 128 * 4, stream);
    hipMemsetAsync(pmud, 0, NG * 128 * 4, stream);
    hipMemsetAsync(pu1, 0, NG * 128 * 4, stream);
    hipMemsetAsync(pd1, 0, NG * 128 * 4, stream);
    hipMemsetAsync(cgu, 0, NG * 4, stream);
    hipMemsetAsync(cgd, 0, NG * 4, stream);
    int gA = (N + 3) / 4;
    aggpool_kernel<<<gA, 256, 0, stream>>>(d1, rp_du, csr_du, batch_u, N, pmdu);
    aggpool_kernel<<<gA, 256, 0, stream>>>(u1, rp_uu, csr_uu, batch_u, N, pmuu);
    aggpool_kernel<<<gA, 256, 0, stream>>>(u1, rp_ud, csr_ud, batch_d, N, pmud);
    rowpool_kernel<<<2048, 256, 0, stream>>>(u1, batch_u, N, pu1);
    rowpool_kernel<<<2048, 256, 0, stream>>>(d1, batch_d, N, pd1);
    hist_kernel<<<128, 256, 0, stream>>>(batch_u, N, cgu);
    hist_kernel<<<128, 256, 0, stream>>>(batch_d, N, cgd);

    // ---- graph-level layer-2 matmuls + MLP + log_softmax ----
    final_kernel<<<NG, 128, 0, stream>>>(pmdu, pmuu, pmud, pu1, pd1, cgu, cgd,
                                         Wl2_du, bl2_du, Wr2_du,
                                         Wl2_uu, bl2_uu, Wr2_uu,
                                         Wl2_ud, bl2_ud, Wr2_ud,
                                         W1, b1, W2, b2, (float*)d_out);
}

// Round 2
// 2076.614 us; speedup vs baseline: 1.4886x; 1.4886x over previous
//
#include <hip/hip_runtime.h>

#define NG 64   // graphs

// ---------------- histogram (int atomics) — edge-dst only ----------------
__global__ void hist_kernel(const int* __restrict__ idx, int n, int* __restrict__ cnt) {
    int i = blockIdx.x * blockDim.x + threadIdx.x;
    int stride = gridDim.x * blockDim.x;
    for (; i < n; i += stride) atomicAdd(&cnt[idx[i]], 1);
}

// ---------------- 3-way exclusive scan -> row_ptr (shfl-based) ----------------
__global__ __launch_bounds__(1024) void scan3_kernel(
    const int* __restrict__ c0, int* __restrict__ r0, int n0,
    const int* __restrict__ c1, int* __restrict__ r1, int n1,
    const int* __restrict__ c2, int* __restrict__ r2, int n2)
{
    const int* c = blockIdx.x == 0 ? c0 : (blockIdx.x == 1 ? c1 : c2);
    int*       r = blockIdx.x == 0 ? r0 : (blockIdx.x == 1 ? r1 : r2);
    int        N = blockIdx.x == 0 ? n0 : (blockIdx.x == 1 ? n1 : n2);
    __shared__ int wsum[16];
    __shared__ int carry;
    int t = threadIdx.x, lane = t & 63, wv = t >> 6;
    if (t == 0) { carry = 0; r[0] = 0; }
    __syncthreads();
    for (int base = 0; base < N; base += 1024) {
        int i = base + t;
        int x = (i < N) ? c[i] : 0;
        #pragma unroll
        for (int off = 1; off < 64; off <<= 1) {
            int u = __shfl_up(x, off, 64);
            if (lane >= off) x += u;
        }
        if (lane == 63) wsum[wv] = x;
        __syncthreads();
        if (wv == 0 && lane < 16) {
            int v = wsum[lane];
            #pragma unroll
            for (int off = 1; off < 16; off <<= 1) {
                int u = __shfl_up(v, off, 64);
                if (lane >= off) v += u;
            }
            wsum[lane] = v;
        }
        __syncthreads();
        int add = carry + (wv > 0 ? wsum[wv - 1] : 0);
        if (i < N) r[i + 1] = x + add;
        int tot = wsum[15];
        __syncthreads();
        if (t == 0) carry += tot;
        __syncthreads();
    }
}

// ---------------- CSR fill ----------------
__global__ void fill_kernel(const int* __restrict__ src, const int* __restrict__ dst, int E,
                            const int* __restrict__ rp, int* __restrict__ cur, int* __restrict__ csr)
{
    int i = blockIdx.x * blockDim.x + threadIdx.x;
    int stride = gridDim.x * blockDim.x;
    for (; i < E; i += stride) {
        int d = dst[i];
        int pos = rp[d] + atomicAdd(&cur[d], 1);
        csr[pos] = src[i];
    }
}

// ---------------- elementwise add (weight/bias sums) ----------------
__global__ void add2_kernel(const float* __restrict__ a, const float* __restrict__ b,
                            float* __restrict__ o, int n) {
    int i = blockIdx.x * blockDim.x + threadIdx.x;
    if (i < n) o[i] = a[i] + b[i];
}

// ---------------- graph boundaries via binary search (batch is sorted) ----------------
__global__ void bounds_kernel(const int* __restrict__ bu, int nu,
                              const int* __restrict__ bd, int nd,
                              int* __restrict__ bndu, int* __restrict__ bndd)
{
    const int* b = blockIdx.x == 0 ? bu : bd;
    int        n = blockIdx.x == 0 ? nu : nd;
    int*       o = blockIdx.x == 0 ? bndu : bndd;
    int g = threadIdx.x;
    if (g > NG) return;
    int lo = 0, hi = n;
    while (lo < hi) { int m = (lo + hi) >> 1; if (b[m] < g) lo = m + 1; else hi = m; }
    o[g] = lo;
}

// ---------------- fused (CSR-mean | dense) x [128x128] GEMM ----------------
template<bool CSRMEAN, bool ACC, bool BIAS, bool RELU>
__global__ __launch_bounds__(256, 2) void gemm_kernel(
    const float* __restrict__ A, int M,
    const float* __restrict__ xsrc,
    const int* __restrict__ rp, const int* __restrict__ csr,
    const float* __restrict__ W, const float* __restrict__ bias,
    float* __restrict__ C)
{
    __shared__ float Ws[128 * 128];   // 64 KB
    __shared__ float As[32 * 128];    // 16 KB
    const int t = threadIdx.x;
    const int row0 = blockIdx.x * 32;

    {
        const float4* wg = (const float4*)W;
        float4* wl = (float4*)Ws;
        #pragma unroll
        for (int i = 0; i < 16; ++i) wl[t + 256 * i] = wg[t + 256 * i];
    }
    if (!CSRMEAN) {
        #pragma unroll
        for (int i = 0; i < 4; ++i) {
            int f = t + 256 * i;
            int rr = f >> 5, cv = f & 31;
            int rg = row0 + rr;
            float4 v = make_float4(0.f, 0.f, 0.f, 0.f);
            if (rg < M) v = ((const float4*)A)[rg * 32 + cv];
            *((float4*)&As[rr * 128 + cv * 4]) = v;
        }
    } else {
        int wave = t >> 6, lane = t & 63;
        for (int rr = wave * 8; rr < wave * 8 + 8; ++rr) {
            int rg = row0 + rr;
            float ax = 0.f, ay = 0.f;
            if (rg < M) {
                int s0 = rp[rg], s1 = rp[rg + 1];
                int j = s0;
                for (; j + 4 <= s1; j += 4) {
                    int i0 = csr[j], i1 = csr[j + 1], i2 = csr[j + 2], i3 = csr[j + 3];
                    float2 v0 = *(const float2*)&xsrc[i0 * 128 + lane * 2];
                    float2 v1 = *(const float2*)&xsrc[i1 * 128 + lane * 2];
                    float2 v2 = *(const float2*)&xsrc[i2 * 128 + lane * 2];
                    float2 v3 = *(const float2*)&xsrc[i3 * 128 + lane * 2];
                    ax += (v0.x + v1.x) + (v2.x + v3.x);
                    ay += (v0.y + v1.y) + (v2.y + v3.y);
                }
                for (; j < s1; ++j) {
                    float2 v = *(const float2*)&xsrc[csr[j] * 128 + lane * 2];
                    ax += v.x; ay += v.y;
                }
                int deg = s1 - s0;
                float sc = 1.f / (float)(deg > 1 ? deg : 1);
                ax *= sc; ay *= sc;
            }
            float2 o2; o2.x = ax; o2.y = ay;
            *((float2*)&As[rr * 128 + lane * 2]) = o2;
        }
    }
    __syncthreads();

    const int tx = t & 31, ty = t >> 5;
    float acc[4][4];
    #pragma unroll
    for (int i = 0; i < 4; ++i) { acc[i][0] = 0.f; acc[i][1] = 0.f; acc[i][2] = 0.f; acc[i][3] = 0.f; }

    #pragma unroll 8
    for (int k = 0; k < 128; ++k) {
        float4 w4 = *((const float4*)&Ws[k * 128 + tx * 4]);
        #pragma unroll
        for (int i = 0; i < 4; ++i) {
            float a = As[(ty * 4 + i) * 128 + k];
            acc[i][0] += a * w4.x;
            acc[i][1] += a * w4.y;
            acc[i][2] += a * w4.z;
            acc[i][3] += a * w4.w;
        }
    }

    float4 bv = make_float4(0.f, 0.f, 0.f, 0.f);
    if (BIAS) bv = *((const float4*)&bias[tx * 4]);
    #pragma unroll
    for (int i = 0; i < 4; ++i) {
        int rg = row0 + ty * 4 + i;
        if (rg >= M) continue;
        float4 res;
        res.x = acc[i][0]; res.y = acc[i][1]; res.z = acc[i][2]; res.w = acc[i][3];
        if (BIAS) { res.x += bv.x; res.y += bv.y; res.z += bv.z; res.w += bv.w; }
        if (ACC) {
            float4 cc = ((const float4*)C)[rg * 32 + tx];
            res.x += cc.x; res.y += cc.y; res.z += cc.z; res.w += cc.w;
        }
        if (RELU) {
            res.x = fmaxf(res.x, 0.f); res.y = fmaxf(res.y, 0.f);
            res.z = fmaxf(res.z, 0.f); res.w = fmaxf(res.w, 0.f);
        }
        ((float4*)C)[rg * 32 + tx] = res;
    }
}

// ---------------- build C[src][g] += 1/deg[dst], g = batch[dst] ----------------
__global__ void cbuild_kernel(const int* __restrict__ src, const int* __restrict__ dst, int E,
                              const int* __restrict__ deg, const int* __restrict__ batch,
                              float* __restrict__ C)
{
    int i = blockIdx.x * blockDim.x + threadIdx.x;
    int stride = gridDim.x * blockDim.x;
    for (; i < E; i += stride) {
        int d = dst[i];
        int g = batch[d];
        float w = 1.f / (float)deg[d];
        atomicAdd(&C[(size_t)src[i] * NG + g], w);
    }
}

// ---------------- pooled agg = C^T @ X, block-partial version ----------------
__global__ __launch_bounds__(256) void poolgemm_partial(
    const float* __restrict__ C, const float* __restrict__ X, int N,
    float* __restrict__ P /* [gridDim.x][64][128] */)
{
    int t = threadIdx.x;
    int c4 = t & 31;             // float4 col group
    int g0 = (t >> 5) * 8;       // 8 graphs per thread
    int rows_per = (N + gridDim.x - 1) / gridDim.x;
    int r0 = blockIdx.x * rows_per;
    int r1 = min(N, r0 + rows_per);
    float4 acc[8];
    #pragma unroll
    for (int i = 0; i < 8; ++i) acc[i] = make_float4(0.f, 0.f, 0.f, 0.f);
    for (int r = r0; r < r1; ++r) {
        float4 xv = ((const float4*)X)[r * 32 + c4];
        const float* crow = C + (size_t)r * NG;
        #pragma unroll
        for (int i = 0; i < 8; ++i) {
            float w = crow[g0 + i];
            acc[i].x += w * xv.x; acc[i].y += w * xv.y;
            acc[i].z += w * xv.z; acc[i].w += w * xv.w;
        }
    }
    float4* out = (float4*)(P + (size_t)blockIdx.x * NG * 128);
    #pragma unroll
    for (int i = 0; i < 8; ++i) out[(g0 + i) * 32 + c4] = acc[i];
}

__global__ void reduce_partials(const float* __restrict__ P, int nblk, float* __restrict__ out) {
    int i = blockIdx.x * blockDim.x + threadIdx.x;   // over 64*128
    if (i >= NG * 128) return;
    float s = 0.f;
    for (int b = 0; b < nblk; ++b) s += P[(size_t)b * NG * 128 + i];
    out[i] = s;
}

// ---------------- per-graph row-sum pool (batch sorted -> contiguous ranges) ----------------
__global__ __launch_bounds__(256) void rowpool_kernel(const float* __restrict__ x,
                                                      const int* __restrict__ bnd,
                                                      float* __restrict__ pool)
{
    int g = blockIdx.x & 63, chunk = blockIdx.x >> 6;   // 4 chunks per graph
    int lo = bnd[g], hi = bnd[g + 1];
    int col = threadIdx.x & 127, half = threadIdx.x >> 7;
    float s = 0.f;
    for (int r = lo + chunk * 2 + half; r < hi; r += 8) s += x[(size_t)r * 128 + col];
    __shared__ float ls[256];
    ls[threadIdx.x] = s;
    __syncthreads();
    if (half == 0) atomicAdd(&pool[g * 128 + col], ls[col] + ls[128 + col]);
}

// ---------------- final: layer-2 matmuls at graph level + MLP + log_softmax ----------------
__global__ __launch_bounds__(128) void final_kernel(
    const float* __restrict__ pmdu, const float* __restrict__ pmuu, const float* __restrict__ pmud,
    const float* __restrict__ pu1,  const float* __restrict__ pd1,
    const int* __restrict__ bndu, const int* __restrict__ bndd,
    const float* __restrict__ Wl2_du, const float* __restrict__ bl2_du, const float* __restrict__ Wr2_du,
    const float* __restrict__ Wl2_uu, const float* __restrict__ bl2_uu, const float* __restrict__ Wr2_uu,
    const float* __restrict__ Wl2_ud, const float* __restrict__ bl2_ud, const float* __restrict__ Wr2_ud,
    const float* __restrict__ W1, const float* __restrict__ b1,
    const float* __restrict__ W2, const float* __restrict__ b2,
    float* __restrict__ out)
{
    int g = blockIdx.x, t = threadIdx.x;
    __shared__ float smdu[128], smuu[128], smud[128], su1[128], sd1[128];
    __shared__ float xrow[256], h[128], lg[2];
    smdu[t] = pmdu[g * 128 + t];
    smuu[t] = pmuu[g * 128 + t];
    smud[t] = pmud[g * 128 + t];
    su1[t]  = pu1[g * 128 + t];
    sd1[t]  = pd1[g * 128 + t];
    __syncthreads();
    float ncu = (float)(bndu[g + 1] - bndu[g]);
    float ncd = (float)(bndd[g + 1] - bndd[g]);
    float cu = ncu > 1.f ? ncu : 1.f, cd = ncd > 1.f ? ncd : 1.f;
    float accu = ncu * (bl2_du[t] + bl2_uu[t]);
    float accd = ncd * bl2_ud[t];
    for (int k = 0; k < 128; ++k) {
        accu += smdu[k] * Wl2_du[k * 128 + t]
              + smuu[k] * Wl2_uu[k * 128 + t]
              + su1[k]  * (Wr2_du[k * 128 + t] + Wr2_uu[k * 128 + t]);
        accd += smud[k] * Wl2_ud[k * 128 + t]
              + sd1[k]  * Wr2_ud[k * 128 + t];
    }
    xrow[t]       = accu / cu;
    xrow[128 + t] = accd / cd;
    __syncthreads();
    float hh = b1[t];
    for (int k = 0; k < 256; ++k) hh += xrow[k] * W1[k * 128 + t];
    h[t] = fmaxf(hh, 0.f);
    __syncthreads();
    if (t < 2) {
        float l = b2[t];
        for (int k = 0; k < 128; ++k) l += h[k] * W2[k * 2 + t];
        lg[t] = l;
    }
    __syncthreads();
    if (t == 0) {
        float m = fmaxf(lg[0], lg[1]);
        float lse = m + logf(expf(lg[0] - m) + expf(lg[1] - m));
        out[g * 2 + 0] = lg[0] - lse;
        out[g * 2 + 1] = lg[1] - lse;
    }
}

extern "C" void kernel_launch(void* const* d_in, const int* in_sizes, int n_in,
                              void* d_out, int out_size, void* d_ws, size_t ws_size,
                              hipStream_t stream)
{
    const float* x_user = (const float*)d_in[0];
    const float* x_drug = (const float*)d_in[1];
    const int* ei_ud = (const int*)d_in[2];
    const int* ei_du = (const int*)d_in[3];
    const int* ei_uu = (const int*)d_in[4];
    const int* batch_u = (const int*)d_in[5];
    const int* batch_d = (const int*)d_in[6];
    const float* Wl1_ud = (const float*)d_in[7];  const float* bl1_ud = (const float*)d_in[8];  const float* Wr1_ud = (const float*)d_in[9];
    const float* Wl1_du = (const float*)d_in[10]; const float* bl1_du = (const float*)d_in[11]; const float* Wr1_du = (const float*)d_in[12];
    const float* Wl1_uu = (const float*)d_in[13]; const float* bl1_uu = (const float*)d_in[14]; const float* Wr1_uu = (const float*)d_in[15];
    const float* Wl2_ud = (const float*)d_in[16]; const float* bl2_ud = (const float*)d_in[17]; const float* Wr2_ud = (const float*)d_in[18];
    const float* Wl2_du = (const float*)d_in[19]; const float* bl2_du = (const float*)d_in[20]; const float* Wr2_du = (const float*)d_in[21];
    const float* Wl2_uu = (const float*)d_in[22]; const float* bl2_uu = (const float*)d_in[23]; const float* Wr2_uu = (const float*)d_in[24];
    const float* W1 = (const float*)d_in[25]; const float* b1 = (const float*)d_in[26];
    const float* W2 = (const float*)d_in[27]; const float* b2 = (const float*)d_in[28];
    (void)n_in; (void)out_size; (void)ws_size;

    const int Nu = in_sizes[0] / 128;
    const int Nd = in_sizes[1] / 128;
    const int E_ud = in_sizes[2] / 2;
    const int E_du = in_sizes[3] / 2;
    const int E_uu = in_sizes[4] / 2;

    char* ws = (char*)d_ws;
    size_t off = 0;
    auto alloc = [&](size_t bytes) -> void* {
        void* p = ws + off;
        off = (off + bytes + 255) & ~(size_t)255;
        return p;
    };
    int* csr_ud = (int*)alloc((size_t)E_ud * 4);
    int* csr_du = (int*)alloc((size_t)E_du * 4);
    int* csr_uu = (int*)alloc((size_t)E_uu * 4);
    int* rp_ud = (int*)alloc((size_t)(Nd + 1) * 4);
    int* rp_du = (int*)alloc((size_t)(Nu + 1) * 4);
    int* rp_uu = (int*)alloc((size_t)(Nu + 1) * 4);
    int* deg_ud = (int*)alloc((size_t)Nd * 4);
    int* deg_du = (int*)alloc((size_t)Nu * 4);
    int* deg_uu = (int*)alloc((size_t)Nu * 4);
    int* cur    = (int*)alloc((size_t)(Nu > Nd ? Nu : Nd) * 4);
    float* u1 = (float*)alloc((size_t)Nu * 128 * 4);
    float* d1 = (float*)alloc((size_t)Nd * 128 * 4);
    float* C_du = (float*)alloc((size_t)Nd * NG * 4);   // src=drug
    float* C_uu = (float*)alloc((size_t)Nu * NG * 4);   // src=user
    float* C_ud = (float*)alloc((size_t)Nu * NG * 4);   // src=user
    float* pmdu = (float*)alloc(NG * 128 * 4);
    float* pmuu = (float*)alloc(NG * 128 * 4);
    float* pmud = (float*)alloc(NG * 128 * 4);
    float* pu1  = (float*)alloc(NG * 128 * 4);
    float* pd1  = (float*)alloc(NG * 128 * 4);
    int* bnd_u = (int*)alloc((NG + 1) * 4);
    int* bnd_d = (int*)alloc((NG + 1) * 4);
    float* Wr1s_u = (float*)alloc(128 * 128 * 4);
    float* b1s_u  = (float*)alloc(128 * 4);

    const int* dst_ud = ei_ud + E_ud;
    const int* dst_du = ei_du + E_du;
    const int* dst_uu = ei_uu + E_uu;

    const int PBLK = 128;   // partial-pool blocks; partials overlay the CSR arrays (dead by then)
    float* P_mdu = (float*)csr_ud;   // PBLK*8192*4 = 4 MB each, csr arrays are 6.4 MB
    float* P_muu = (float*)csr_du;
    float* P_mud = (float*)csr_uu;

    // ---- CSR build ----
    hipMemsetAsync(deg_ud, 0, (size_t)Nd * 4, stream);
    hipMemsetAsync(deg_du, 0, (size_t)Nu * 4, stream);
    hipMemsetAsync(deg_uu, 0, (size_t)Nu * 4, stream);
    hist_kernel<<<2048, 256, 0, stream>>>(dst_ud, E_ud, deg_ud);
    hist_kernel<<<2048, 256, 0, stream>>>(dst_du, E_du, deg_du);
    hist_kernel<<<2048, 256, 0, stream>>>(dst_uu, E_uu, deg_uu);
    scan3_kernel<<<3, 1024, 0, stream>>>(deg_ud, rp_ud, Nd, deg_du, rp_du, Nu, deg_uu, rp_uu, Nu);
    hipMemsetAsync(cur, 0, (size_t)Nd * 4, stream);
    fill_kernel<<<2048, 256, 0, stream>>>(ei_ud, dst_ud, E_ud, rp_ud, cur, csr_ud);
    hipMemsetAsync(cur, 0, (size_t)Nu * 4, stream);
    fill_kernel<<<2048, 256, 0, stream>>>(ei_du, dst_du, E_du, rp_du, cur, csr_du);
    hipMemsetAsync(cur, 0, (size_t)Nu * 4, stream);
    fill_kernel<<<2048, 256, 0, stream>>>(ei_uu, dst_uu, E_uu, rp_uu, cur, csr_uu);

    // ---- graph boundaries (batch arrays are sorted) ----
    bounds_kernel<<<2, NG + 1, 0, stream>>>(batch_u, Nu, batch_d, Nd, bnd_u, bnd_d);

    // ---- weight/bias sums for the doubled root term on user nodes ----
    add2_kernel<<<64, 256, 0, stream>>>(Wr1_du, Wr1_uu, Wr1s_u, 128 * 128);
    add2_kernel<<<1, 128, 0, stream>>>(bl1_du, bl1_uu, b1s_u, 128);

    // ---- layer 1 (full-size, fused CSR-mean GEMMs) ----
    int gBu = (Nu + 31) / 32, gBd = (Nd + 31) / 32;
    gemm_kernel<false, false, true,  false><<<gBu, 256, 0, stream>>>(x_user, Nu, nullptr, nullptr, nullptr, Wr1s_u, b1s_u, u1);
    gemm_kernel<true,  true,  false, false><<<gBu, 256, 0, stream>>>(nullptr, Nu, x_drug, rp_du, csr_du, Wl1_du, nullptr, u1);
    gemm_kernel<true,  true,  false, true ><<<gBu, 256, 0, stream>>>(nullptr, Nu, x_user, rp_uu, csr_uu, Wl1_uu, nullptr, u1);
    gemm_kernel<false, false, true,  false><<<gBd, 256, 0, stream>>>(x_drug, Nd, nullptr, nullptr, nullptr, Wr1_ud, bl1_ud, d1);
    gemm_kernel<true,  true,  false, true ><<<gBd, 256, 0, stream>>>(nullptr, Nd, x_user, rp_ud, csr_ud, Wl1_ud, nullptr, d1);

    // ---- layer 2: pooled aggregation as C^T @ x1 ----
    hipMemsetAsync(C_du, 0, (size_t)Nd * NG * 4, stream);
    hipMemsetAsync(C_uu, 0, (size_t)Nu * NG * 4, stream);
    hipMemsetAsync(C_ud, 0, (size_t)Nu * NG * 4, stream);
    cbuild_kernel<<<2048, 256, 0, stream>>>(ei_du, dst_du, E_du, deg_du, batch_u, C_du);
    cbuild_kernel<<<2048, 256, 0, stream>>>(ei_uu, dst_uu, E_uu, deg_uu, batch_u, C_uu);
    cbuild_kernel<<<2048, 256, 0, stream>>>(ei_ud, dst_ud, E_ud, deg_ud, batch_d, C_ud);

    // partials overlay csr arrays (csr no longer needed after layer-1 gemms)
    poolgemm_partial<<<PBLK, 256, 0, stream>>>(C_du, d1, Nd, P_mdu);
    poolgemm_partial<<<PBLK, 256, 0, stream>>>(C_uu, u1, Nu, P_muu);
    poolgemm_partial<<<PBLK, 256, 0, stream>>>(C_ud, u1, Nu, P_mud);
    reduce_partials<<<(NG * 128 + 255) / 256, 256, 0, stream>>>(P_mdu, PBLK, pmdu);
    reduce_partials<<<(NG * 128 + 255) / 256, 256, 0, stream>>>(P_muu, PBLK, pmuu);
    reduce_partials<<<(NG * 128 + 255) / 256, 256, 0, stream>>>(P_mud, PBLK, pmud);

    // ---- root-term pools: per-graph contiguous row sums ----
    hipMemsetAsync(pu1, 0, NG * 128 * 4, stream);
    hipMemsetAsync(pd1, 0, NG * 128 * 4, stream);
    rowpool_kernel<<<NG * 4, 256, 0, stream>>>(u1, bnd_u, pu1);
    rowpool_kernel<<<NG * 4, 256, 0, stream>>>(d1, bnd_d, pd1);

    // ---- graph-level layer-2 matmuls + MLP + log_softmax ----
    final_kernel<<<NG, 128, 0, stream>>>(pmdu, pmuu, pmud, pu1, pd1, bnd_u, bnd_d,
                                         Wl2_du, bl2_du, Wr2_du,
                                         Wl2_uu, bl2_uu, Wr2_uu,
                                         Wl2_ud, bl2_ud, Wr2_ud,
                                         W1, b1, W2, b2, (float*)d_out);
}

// Round 3
// 1684.696 us; speedup vs baseline: 1.8349x; 1.2326x over previous
//
#include <hip/hip_runtime.h>

#define NG 64   // graphs

__device__ __forceinline__ ushort f2bf(float f) {
    unsigned int b = __float_as_uint(f);
    b += 0x7fffu + ((b >> 16) & 1u);   // RTNE
    return (ushort)(b >> 16);
}

// ---------------- histogram (int atomics) — edge-dst only ----------------
__global__ void hist_kernel(const int* __restrict__ idx, int n, int* __restrict__ cnt) {
    int i = blockIdx.x * blockDim.x + threadIdx.x;
    int stride = gridDim.x * blockDim.x;
    for (; i < n; i += stride) atomicAdd(&cnt[idx[i]], 1);
}

// ---------------- 3-way exclusive scan -> row_ptr (shfl-based) ----------------
__global__ __launch_bounds__(1024) void scan3_kernel(
    const int* __restrict__ c0, int* __restrict__ r0, int n0,
    const int* __restrict__ c1, int* __restrict__ r1, int n1,
    const int* __restrict__ c2, int* __restrict__ r2, int n2)
{
    const int* c = blockIdx.x == 0 ? c0 : (blockIdx.x == 1 ? c1 : c2);
    int*       r = blockIdx.x == 0 ? r0 : (blockIdx.x == 1 ? r1 : r2);
    int        N = blockIdx.x == 0 ? n0 : (blockIdx.x == 1 ? n1 : n2);
    __shared__ int wsum[16];
    __shared__ int carry;
    int t = threadIdx.x, lane = t & 63, wv = t >> 6;
    if (t == 0) { carry = 0; r[0] = 0; }
    __syncthreads();
    for (int base = 0; base < N; base += 1024) {
        int i = base + t;
        int x = (i < N) ? c[i] : 0;
        #pragma unroll
        for (int off = 1; off < 64; off <<= 1) {
            int u = __shfl_up(x, off, 64);
            if (lane >= off) x += u;
        }
        if (lane == 63) wsum[wv] = x;
        __syncthreads();
        if (wv == 0 && lane < 16) {
            int v = wsum[lane];
            #pragma unroll
            for (int off = 1; off < 16; off <<= 1) {
                int u = __shfl_up(v, off, 64);
                if (lane >= off) v += u;
            }
            wsum[lane] = v;
        }
        __syncthreads();
        int add = carry + (wv > 0 ? wsum[wv - 1] : 0);
        if (i < N) r[i + 1] = x + add;
        int tot = wsum[15];
        __syncthreads();
        if (t == 0) carry += tot;
        __syncthreads();
    }
}

// ---------------- CSR fill ----------------
__global__ void fill_kernel(const int* __restrict__ src, const int* __restrict__ dst, int E,
                            const int* __restrict__ rp, int* __restrict__ cur, int* __restrict__ csr)
{
    int i = blockIdx.x * blockDim.x + threadIdx.x;
    int stride = gridDim.x * blockDim.x;
    for (; i < E; i += stride) {
        int d = dst[i];
        int pos = rp[d] + atomicAdd(&cur[d], 1);
        csr[pos] = src[i];
    }
}

// ---------------- elementwise add (weight/bias sums) ----------------
__global__ void add2_kernel(const float* __restrict__ a, const float* __restrict__ b,
                            float* __restrict__ o, int n) {
    int i = blockIdx.x * blockDim.x + threadIdx.x;
    if (i < n) o[i] = a[i] + b[i];
}

// ---------------- f32 -> bf16 conversion (4 elems/thread) ----------------
__global__ void cvt_kernel(const float* __restrict__ x, ushort* __restrict__ o, int n4) {
    int i = blockIdx.x * blockDim.x + threadIdx.x;
    if (i >= n4) return;
    float4 v = ((const float4*)x)[i];
    ushort4 r;
    r.x = f2bf(v.x); r.y = f2bf(v.y); r.z = f2bf(v.z); r.w = f2bf(v.w);
    ((ushort4*)o)[i] = r;
}

// ---------------- graph boundaries via binary search (batch is sorted) ----------------
__global__ void bounds_kernel(const int* __restrict__ bu, int nu,
                              const int* __restrict__ bd, int nd,
                              int* __restrict__ bndu, int* __restrict__ bndd)
{
    const int* b = blockIdx.x == 0 ? bu : bd;
    int        n = blockIdx.x == 0 ? nu : nd;
    int*       o = blockIdx.x == 0 ? bndu : bndd;
    int g = threadIdx.x;
    if (g > NG) return;
    int lo = 0, hi = n;
    while (lo < hi) { int m = (lo + hi) >> 1; if (b[m] < g) lo = m + 1; else hi = m; }
    o[g] = lo;
}

// ---------------- CSR mean aggregation: bf16 gather -> bf16 mean rows ----------------
// one wave per dst row; lane covers 2 columns (one packed uint)
__global__ __launch_bounds__(256) void agg_kernel(
    const ushort* __restrict__ xb,   // [Nsrc,128] bf16
    const int* __restrict__ rp, const int* __restrict__ csr, int M,
    ushort* __restrict__ mean /* [M,128] bf16 */)
{
    int wave = threadIdx.x >> 6, lane = threadIdx.x & 63;
    int row = blockIdx.x * 4 + wave;
    if (row >= M) return;
    int s0 = rp[row], s1 = rp[row + 1];
    float ax = 0.f, ay = 0.f;
    int j = s0;
    for (; j + 4 <= s1; j += 4) {
        int i0 = csr[j], i1 = csr[j + 1], i2 = csr[j + 2], i3 = csr[j + 3];
        unsigned int v0 = *(const unsigned int*)&xb[(size_t)i0 * 128 + lane * 2];
        unsigned int v1 = *(const unsigned int*)&xb[(size_t)i1 * 128 + lane * 2];
        unsigned int v2 = *(const unsigned int*)&xb[(size_t)i2 * 128 + lane * 2];
        unsigned int v3 = *(const unsigned int*)&xb[(size_t)i3 * 128 + lane * 2];
        ax += __uint_as_float(v0 << 16) + __uint_as_float(v1 << 16)
            + __uint_as_float(v2 << 16) + __uint_as_float(v3 << 16);
        ay += __uint_as_float(v0 & 0xffff0000u) + __uint_as_float(v1 & 0xffff0000u)
            + __uint_as_float(v2 & 0xffff0000u) + __uint_as_float(v3 & 0xffff0000u);
    }
    for (; j < s1; ++j) {
        unsigned int v = *(const unsigned int*)&xb[(size_t)csr[j] * 128 + lane * 2];
        ax += __uint_as_float(v << 16);
        ay += __uint_as_float(v & 0xffff0000u);
    }
    int deg = s1 - s0;
    float sc = 1.f / (float)(deg > 1 ? deg : 1);
    unsigned int pk = (unsigned int)f2bf(ax * sc) | ((unsigned int)f2bf(ay * sc) << 16);
    *(unsigned int*)&mean[(size_t)row * 128 + lane * 2] = pk;
}

// ---------------- dense [M,128]@[128,128] GEMM; A is f32 (AMODE=0) or bf16 (AMODE=1) ----------------
template<int AMODE, bool ACC, bool BIAS, bool RELU>
__global__ __launch_bounds__(256, 2) void gemm_kernel(
    const float* __restrict__ Af, const ushort* __restrict__ Ab, int M,
    const float* __restrict__ W, const float* __restrict__ bias,
    float* __restrict__ C)
{
    __shared__ float Ws[128 * 128];   // 64 KB
    __shared__ float As[32 * 128];    // 16 KB
    const int t = threadIdx.x;
    const int row0 = blockIdx.x * 32;

    {
        const float4* wg = (const float4*)W;
        float4* wl = (float4*)Ws;
        #pragma unroll
        for (int i = 0; i < 16; ++i) wl[t + 256 * i] = wg[t + 256 * i];
    }
    if (AMODE == 0) {
        #pragma unroll
        for (int i = 0; i < 4; ++i) {
            int f = t + 256 * i;
            int rr = f >> 5, cv = f & 31;
            int rg = row0 + rr;
            float4 v = make_float4(0.f, 0.f, 0.f, 0.f);
            if (rg < M) v = ((const float4*)Af)[(size_t)rg * 32 + cv];
            *((float4*)&As[rr * 128 + cv * 4]) = v;
        }
    } else {
        #pragma unroll
        for (int i = 0; i < 2; ++i) {
            int f = t + 256 * i;          // 512 uint4 = 32 rows x 16
            int rr = f >> 4, c16 = f & 15;
            int rg = row0 + rr;
            uint4 v = make_uint4(0u, 0u, 0u, 0u);
            if (rg < M) v = ((const uint4*)Ab)[(size_t)rg * 16 + c16];
            float* dst = &As[rr * 128 + c16 * 8];
            dst[0] = __uint_as_float(v.x << 16); dst[1] = __uint_as_float(v.x & 0xffff0000u);
            dst[2] = __uint_as_float(v.y << 16); dst[3] = __uint_as_float(v.y & 0xffff0000u);
            dst[4] = __uint_as_float(v.z << 16); dst[5] = __uint_as_float(v.z & 0xffff0000u);
            dst[6] = __uint_as_float(v.w << 16); dst[7] = __uint_as_float(v.w & 0xffff0000u);
        }
    }
    __syncthreads();

    const int tx = t & 31, ty = t >> 5;
    float acc[4][4];
    #pragma unroll
    for (int i = 0; i < 4; ++i) { acc[i][0] = 0.f; acc[i][1] = 0.f; acc[i][2] = 0.f; acc[i][3] = 0.f; }

    #pragma unroll 8
    for (int k = 0; k < 128; ++k) {
        float4 w4 = *((const float4*)&Ws[k * 128 + tx * 4]);
        #pragma unroll
        for (int i = 0; i < 4; ++i) {
            float a = As[(ty * 4 + i) * 128 + k];
            acc[i][0] += a * w4.x;
            acc[i][1] += a * w4.y;
            acc[i][2] += a * w4.z;
            acc[i][3] += a * w4.w;
        }
    }

    float4 bv = make_float4(0.f, 0.f, 0.f, 0.f);
    if (BIAS) bv = *((const float4*)&bias[tx * 4]);
    #pragma unroll
    for (int i = 0; i < 4; ++i) {
        int rg = row0 + ty * 4 + i;
        if (rg >= M) continue;
        float4 res;
        res.x = acc[i][0]; res.y = acc[i][1]; res.z = acc[i][2]; res.w = acc[i][3];
        if (BIAS) { res.x += bv.x; res.y += bv.y; res.z += bv.z; res.w += bv.w; }
        if (ACC) {
            float4 cc = ((const float4*)C)[(size_t)rg * 32 + tx];
            res.x += cc.x; res.y += cc.y; res.z += cc.z; res.w += cc.w;
        }
        if (RELU) {
            res.x = fmaxf(res.x, 0.f); res.y = fmaxf(res.y, 0.f);
            res.z = fmaxf(res.z, 0.f); res.w = fmaxf(res.w, 0.f);
        }
        ((float4*)C)[(size_t)rg * 32 + tx] = res;
    }
}

// ---------------- build C[src][g] += 1/deg[dst], g = batch[dst] ----------------
__global__ void cbuild_kernel(const int* __restrict__ src, const int* __restrict__ dst, int E,
                              const int* __restrict__ deg, const int* __restrict__ batch,
                              float* __restrict__ C)
{
    int i = blockIdx.x * blockDim.x + threadIdx.x;
    int stride = gridDim.x * blockDim.x;
    for (; i < E; i += stride) {
        int d = dst[i];
        int g = batch[d];
        float w = 1.f / (float)deg[d];
        atomicAdd(&C[(size_t)src[i] * NG + g], w);
    }
}

// ---------------- pooled agg = C^T @ X, block-partial version ----------------
__global__ __launch_bounds__(256) void poolgemm_partial(
    const float* __restrict__ C, const float* __restrict__ X, int N,
    float* __restrict__ P /* [gridDim.x][64][128] */)
{
    int t = threadIdx.x;
    int c4 = t & 31;
    int g0 = (t >> 5) * 8;
    int rows_per = (N + gridDim.x - 1) / gridDim.x;
    int r0 = blockIdx.x * rows_per;
    int r1 = min(N, r0 + rows_per);
    float4 acc[8];
    #pragma unroll
    for (int i = 0; i < 8; ++i) acc[i] = make_float4(0.f, 0.f, 0.f, 0.f);
    for (int r = r0; r < r1; ++r) {
        float4 xv = ((const float4*)X)[(size_t)r * 32 + c4];
        const float* crow = C + (size_t)r * NG;
        #pragma unroll
        for (int i = 0; i < 8; ++i) {
            float w = crow[g0 + i];
            acc[i].x += w * xv.x; acc[i].y += w * xv.y;
            acc[i].z += w * xv.z; acc[i].w += w * xv.w;
        }
    }
    float4* out = (float4*)(P + (size_t)blockIdx.x * NG * 128);
    #pragma unroll
    for (int i = 0; i < 8; ++i) out[(g0 + i) * 32 + c4] = acc[i];
}

__global__ void reduce_partials(const float* __restrict__ P, int nblk, float* __restrict__ out) {
    int i = blockIdx.x * blockDim.x + threadIdx.x;
    if (i >= NG * 128) return;
    float s = 0.f;
    for (int b = 0; b < nblk; ++b) s += P[(size_t)b * NG * 128 + i];
    out[i] = s;
}

// ---------------- per-graph row-sum pool (batch sorted -> contiguous ranges) ----------------
__global__ __launch_bounds__(256) void rowpool_kernel(const float* __restrict__ x,
                                                      const int* __restrict__ bnd,
                                                      float* __restrict__ pool)
{
    int g = blockIdx.x & 63, chunk = blockIdx.x >> 6;
    int lo = bnd[g], hi = bnd[g + 1];
    int col = threadIdx.x & 127, half = threadIdx.x >> 7;
    float s = 0.f;
    for (int r = lo + chunk * 2 + half; r < hi; r += 8) s += x[(size_t)r * 128 + col];
    __shared__ float ls[256];
    ls[threadIdx.x] = s;
    __syncthreads();
    if (half == 0) atomicAdd(&pool[g * 128 + col], ls[col] + ls[128 + col]);
}

// ---------------- final: layer-2 matmuls at graph level + MLP + log_softmax ----------------
__global__ __launch_bounds__(128) void final_kernel(
    const float* __restrict__ pmdu, const float* __restrict__ pmuu, const float* __restrict__ pmud,
    const float* __restrict__ pu1,  const float* __restrict__ pd1,
    const int* __restrict__ bndu, const int* __restrict__ bndd,
    const float* __restrict__ Wl2_du, const float* __restrict__ bl2_du, const float* __restrict__ Wr2_du,
    const float* __restrict__ Wl2_uu, const float* __restrict__ bl2_uu, const float* __restrict__ Wr2_uu,
    const float* __restrict__ Wl2_ud, const float* __restrict__ bl2_ud, const float* __restrict__ Wr2_ud,
    const float* __restrict__ W1, const float* __restrict__ b1,
    const float* __restrict__ W2, const float* __restrict__ b2,
    float* __restrict__ out)
{
    int g = blockIdx.x, t = threadIdx.x;
    __shared__ float smdu[128], smuu[128], smud[128], su1[128], sd1[128];
    __shared__ float xrow[256], h[128], lg[2];
    smdu[t] = pmdu[g * 128 + t];
    smuu[t] = pmuu[g * 128 + t];
    smud[t] = pmud[g * 128 + t];
    su1[t]  = pu1[g * 128 + t];
    sd1[t]  = pd1[g * 128 + t];
    __syncthreads();
    float ncu = (float)(bndu[g + 1] - bndu[g]);
    float ncd = (float)(bndd[g + 1] - bndd[g]);
    float cu = ncu > 1.f ? ncu : 1.f, cd = ncd > 1.f ? ncd : 1.f;
    float accu = ncu * (bl2_du[t] + bl2_uu[t]);
    float accd = ncd * bl2_ud[t];
    for (int k = 0; k < 128; ++k) {
        accu += smdu[k] * Wl2_du[k * 128 + t]
              + smuu[k] * Wl2_uu[k * 128 + t]
              + su1[k]  * (Wr2_du[k * 128 + t] + Wr2_uu[k * 128 + t]);
        accd += smud[k] * Wl2_ud[k * 128 + t]
              + sd1[k]  * Wr2_ud[k * 128 + t];
    }
    xrow[t]       = accu / cu;
    xrow[128 + t] = accd / cd;
    __syncthreads();
    float hh = b1[t];
    for (int k = 0; k < 256; ++k) hh += xrow[k] * W1[k * 128 + t];
    h[t] = fmaxf(hh, 0.f);
    __syncthreads();
    if (t < 2) {
        float l = b2[t];
        for (int k = 0; k < 128; ++k) l += h[k] * W2[k * 2 + t];
        lg[t] = l;
    }
    __syncthreads();
    if (t == 0) {
        float m = fmaxf(lg[0], lg[1]);
        float lse = m + logf(expf(lg[0] - m) + expf(lg[1] - m));
        out[g * 2 + 0] = lg[0] - lse;
        out[g * 2 + 1] = lg[1] - lse;
    }
}

extern "C" void kernel_launch(void* const* d_in, const int* in_sizes, int n_in,
                              void* d_out, int out_size, void* d_ws, size_t ws_size,
                              hipStream_t stream)
{
    const float* x_user = (const float*)d_in[0];
    const float* x_drug = (const float*)d_in[1];
    const int* ei_ud = (const int*)d_in[2];
    const int* ei_du = (const int*)d_in[3];
    const int* ei_uu = (const int*)d_in[4];
    const int* batch_u = (const int*)d_in[5];
    const int* batch_d = (const int*)d_in[6];
    const float* Wl1_ud = (const float*)d_in[7];  const float* bl1_ud = (const float*)d_in[8];  const float* Wr1_ud = (const float*)d_in[9];
    const float* Wl1_du = (const float*)d_in[10]; const float* bl1_du = (const float*)d_in[11]; const float* Wr1_du = (const float*)d_in[12];
    const float* Wl1_uu = (const float*)d_in[13]; const float* bl1_uu = (const float*)d_in[14]; const float* Wr1_uu = (const float*)d_in[15];
    const float* Wl2_ud = (const float*)d_in[16]; const float* bl2_ud = (const float*)d_in[17]; const float* Wr2_ud = (const float*)d_in[18];
    const float* Wl2_du = (const float*)d_in[19]; const float* bl2_du = (const float*)d_in[20]; const float* Wr2_du = (const float*)d_in[21];
    const float* Wl2_uu = (const float*)d_in[22]; const float* bl2_uu = (const float*)d_in[23]; const float* Wr2_uu = (const float*)d_in[24];
    const float* W1 = (const float*)d_in[25]; const float* b1 = (const float*)d_in[26];
    const float* W2 = (const float*)d_in[27]; const float* b2 = (const float*)d_in[28];
    (void)n_in; (void)out_size; (void)ws_size;

    const int Nu = in_sizes[0] / 128;
    const int Nd = in_sizes[1] / 128;
    const int E_ud = in_sizes[2] / 2;
    const int E_du = in_sizes[3] / 2;
    const int E_uu = in_sizes[4] / 2;

    char* ws = (char*)d_ws;
    size_t off = 0;
    auto alloc = [&](size_t bytes) -> void* {
        void* p = ws + off;
        off = (off + bytes + 255) & ~(size_t)255;
        return p;
    };
    int* csr_ud = (int*)alloc((size_t)E_ud * 4);
    int* csr_du = (int*)alloc((size_t)E_du * 4);
    int* csr_uu = (int*)alloc((size_t)E_uu * 4);
    int* rp_ud = (int*)alloc((size_t)(Nd + 1) * 4);
    int* rp_du = (int*)alloc((size_t)(Nu + 1) * 4);
    int* rp_uu = (int*)alloc((size_t)(Nu + 1) * 4);
    int* deg_ud = (int*)alloc((size_t)Nd * 4);
    int* deg_du = (int*)alloc((size_t)Nu * 4);
    int* deg_uu = (int*)alloc((size_t)Nu * 4);
    int* cur    = (int*)alloc((size_t)(Nu > Nd ? Nu : Nd) * 4);
    ushort* xb_u = (ushort*)alloc((size_t)Nu * 128 * 2);
    ushort* xb_d = (ushort*)alloc((size_t)Nd * 128 * 2);
    // mean buffers (bf16) — dead after layer-1 GEMMs; C matrices (f32) overlay them 1:1
    ushort* mean_du = (ushort*)alloc((size_t)Nu * 128 * 2);   // src=drug
    ushort* mean_uu = (ushort*)alloc((size_t)Nu * 128 * 2);   // src=user
    ushort* mean_ud = (ushort*)alloc((size_t)Nd * 128 * 2);   // src=user
    float* u1 = (float*)alloc((size_t)Nu * 128 * 4);
    float* d1 = (float*)alloc((size_t)Nd * 128 * 4);
    float* pmdu = (float*)alloc(NG * 128 * 4);
    float* pmuu = (float*)alloc(NG * 128 * 4);
    float* pmud = (float*)alloc(NG * 128 * 4);
    float* pu1  = (float*)alloc(NG * 128 * 4);
    float* pd1  = (float*)alloc(NG * 128 * 4);
    int* bnd_u = (int*)alloc((NG + 1) * 4);
    int* bnd_d = (int*)alloc((NG + 1) * 4);
    float* Wr1s_u = (float*)alloc(128 * 128 * 4);
    float* b1s_u  = (float*)alloc(128 * 4);

    float* C_du = (float*)mean_du;   // [Nd,64] f32 = 12.8MB over [Nu,128] bf16 = 12.8MB
    float* C_uu = (float*)mean_uu;   // [Nu,64]
    float* C_ud = (float*)mean_ud;   // [Nu,64]

    const int* dst_ud = ei_ud + E_ud;
    const int* dst_du = ei_du + E_du;
    const int* dst_uu = ei_uu + E_uu;

    const int PBLK = 128;   // partials overlay csr arrays (dead after agg phase)
    float* P_mdu = (float*)csr_ud;
    float* P_muu = (float*)csr_du;
    float* P_mud = (float*)csr_uu;

    // ---- CSR build ----
    hipMemsetAsync(deg_ud, 0, (size_t)Nd * 4, stream);
    hipMemsetAsync(deg_du, 0, (size_t)Nu * 4, stream);
    hipMemsetAsync(deg_uu, 0, (size_t)Nu * 4, stream);
    hist_kernel<<<2048, 256, 0, stream>>>(dst_ud, E_ud, deg_ud);
    hist_kernel<<<2048, 256, 0, stream>>>(dst_du, E_du, deg_du);
    hist_kernel<<<2048, 256, 0, stream>>>(dst_uu, E_uu, deg_uu);
    scan3_kernel<<<3, 1024, 0, stream>>>(deg_ud, rp_ud, Nd, deg_du, rp_du, Nu, deg_uu, rp_uu, Nu);
    hipMemsetAsync(cur, 0, (size_t)Nd * 4, stream);
    fill_kernel<<<2048, 256, 0, stream>>>(ei_ud, dst_ud, E_ud, rp_ud, cur, csr_ud);
    hipMemsetAsync(cur, 0, (size_t)Nu * 4, stream);
    fill_kernel<<<2048, 256, 0, stream>>>(ei_du, dst_du, E_du, rp_du, cur, csr_du);
    hipMemsetAsync(cur, 0, (size_t)Nu * 4, stream);
    fill_kernel<<<2048, 256, 0, stream>>>(ei_uu, dst_uu, E_uu, rp_uu, cur, csr_uu);

    // ---- graph boundaries, bf16 inputs, weight sums ----
    bounds_kernel<<<2, NG + 1, 0, stream>>>(batch_u, Nu, batch_d, Nd, bnd_u, bnd_d);
    cvt_kernel<<<(Nu * 32 + 255) / 256, 256, 0, stream>>>(x_user, xb_u, Nu * 32);
    cvt_kernel<<<(Nd * 32 + 255) / 256, 256, 0, stream>>>(x_drug, xb_d, Nd * 32);
    add2_kernel<<<64, 256, 0, stream>>>(Wr1_du, Wr1_uu, Wr1s_u, 128 * 128);
    add2_kernel<<<1, 128, 0, stream>>>(bl1_du, bl1_uu, b1s_u, 128);

    // ---- layer-1 aggregation: high-occupancy bf16 gather means ----
    agg_kernel<<<(Nu + 3) / 4, 256, 0, stream>>>(xb_d, rp_du, csr_du, Nu, mean_du);
    agg_kernel<<<(Nu + 3) / 4, 256, 0, stream>>>(xb_u, rp_uu, csr_uu, Nu, mean_uu);
    agg_kernel<<<(Nd + 3) / 4, 256, 0, stream>>>(xb_u, rp_ud, csr_ud, Nd, mean_ud);

    // ---- layer-1 dense GEMMs ----
    int gBu = (Nu + 31) / 32, gBd = (Nd + 31) / 32;
    gemm_kernel<0, false, true,  false><<<gBu, 256, 0, stream>>>(x_user, nullptr, Nu, Wr1s_u, b1s_u, u1);
    gemm_kernel<1, true,  false, false><<<gBu, 256, 0, stream>>>(nullptr, mean_du, Nu, Wl1_du, nullptr, u1);
    gemm_kernel<1, true,  false, true ><<<gBu, 256, 0, stream>>>(nullptr, mean_uu, Nu, Wl1_uu, nullptr, u1);
    gemm_kernel<0, false, true,  false><<<gBd, 256, 0, stream>>>(x_drug, nullptr, Nd, Wr1_ud, bl1_ud, d1);
    gemm_kernel<1, true,  false, true ><<<gBd, 256, 0, stream>>>(nullptr, mean_ud, Nd, Wl1_ud, nullptr, d1);

    // ---- layer 2: pooled aggregation as C^T @ x1 (C overlays means, now dead) ----
    hipMemsetAsync(C_du, 0, (size_t)Nd * NG * 4, stream);
    hipMemsetAsync(C_uu, 0, (size_t)Nu * NG * 4, stream);
    hipMemsetAsync(C_ud, 0, (size_t)Nu * NG * 4, stream);
    cbuild_kernel<<<2048, 256, 0, stream>>>(ei_du, dst_du, E_du, deg_du, batch_u, C_du);
    cbuild_kernel<<<2048, 256, 0, stream>>>(ei_uu, dst_uu, E_uu, deg_uu, batch_u, C_uu);
    cbuild_kernel<<<2048, 256, 0, stream>>>(ei_ud, dst_ud, E_ud, deg_ud, batch_d, C_ud);

    poolgemm_partial<<<PBLK, 256, 0, stream>>>(C_du, d1, Nd, P_mdu);
    poolgemm_partial<<<PBLK, 256, 0, stream>>>(C_uu, u1, Nu, P_muu);
    poolgemm_partial<<<PBLK, 256, 0, stream>>>(C_ud, u1, Nu, P_mud);
    reduce_partials<<<(NG * 128 + 255) / 256, 256, 0, stream>>>(P_mdu, PBLK, pmdu);
    reduce_partials<<<(NG * 128 + 255) / 256, 256, 0, stream>>>(P_muu, PBLK, pmuu);
    reduce_partials<<<(NG * 128 + 255) / 256, 256, 0, stream>>>(P_mud, PBLK, pmud);

    // ---- root-term pools ----
    hipMemsetAsync(pu1, 0, NG * 128 * 4, stream);
    hipMemsetAsync(pd1, 0, NG * 128 * 4, stream);
    rowpool_kernel<<<NG * 4, 256, 0, stream>>>(u1, bnd_u, pu1);
    rowpool_kernel<<<NG * 4, 256, 0, stream>>>(d1, bnd_d, pd1);

    // ---- graph-level layer-2 matmuls + MLP + log_softmax ----
    final_kernel<<<NG, 128, 0, stream>>>(pmdu, pmuu, pmud, pu1, pd1, bnd_u, bnd_d,
                                         Wl2_du, bl2_du, Wr2_du,
                                         Wl2_uu, bl2_uu, Wr2_uu,
                                         Wl2_ud, bl2_ud, Wr2_ud,
                                         W1, b1, W2, b2, (float*)d_out);
}

// Round 4
// 1515.726 us; speedup vs baseline: 2.0395x; 1.1115x over previous
//
#include <hip/hip_runtime.h>

#define NG 64   // graphs

__device__ __forceinline__ ushort f2bf(float f) {
    unsigned int b = __float_as_uint(f);
    b += 0x7fffu + ((b >> 16) & 1u);   // RTNE
    return (ushort)(b >> 16);
}

// ---------------- histogram (int atomics) — edge-dst only ----------------
__global__ void hist_kernel(const int* __restrict__ idx, int n, int* __restrict__ cnt) {
    int i = blockIdx.x * blockDim.x + threadIdx.x;
    int stride = gridDim.x * blockDim.x;
    for (; i < n; i += stride) atomicAdd(&cnt[idx[i]], 1);
}

// ---------------- 3-way exclusive scan -> row_ptr (shfl-based) ----------------
__global__ __launch_bounds__(1024) void scan3_kernel(
    const int* __restrict__ c0, int* __restrict__ r0, int n0,
    const int* __restrict__ c1, int* __restrict__ r1, int n1,
    const int* __restrict__ c2, int* __restrict__ r2, int n2)
{
    const int* c = blockIdx.x == 0 ? c0 : (blockIdx.x == 1 ? c1 : c2);
    int*       r = blockIdx.x == 0 ? r0 : (blockIdx.x == 1 ? r1 : r2);
    int        N = blockIdx.x == 0 ? n0 : (blockIdx.x == 1 ? n1 : n2);
    __shared__ int wsum[16];
    __shared__ int carry;
    int t = threadIdx.x, lane = t & 63, wv = t >> 6;
    if (t == 0) { carry = 0; r[0] = 0; }
    __syncthreads();
    for (int base = 0; base < N; base += 1024) {
        int i = base + t;
        int x = (i < N) ? c[i] : 0;
        #pragma unroll
        for (int off = 1; off < 64; off <<= 1) {
            int u = __shfl_up(x, off, 64);
            if (lane >= off) x += u;
        }
        if (lane == 63) wsum[wv] = x;
        __syncthreads();
        if (wv == 0 && lane < 16) {
            int v = wsum[lane];
            #pragma unroll
            for (int off = 1; off < 16; off <<= 1) {
                int u = __shfl_up(v, off, 64);
                if (lane >= off) v += u;
            }
            wsum[lane] = v;
        }
        __syncthreads();
        int add = carry + (wv > 0 ? wsum[wv - 1] : 0);
        if (i < N) r[i + 1] = x + add;
        int tot = wsum[15];
        __syncthreads();
        if (t == 0) carry += tot;
        __syncthreads();
    }
}

// ---------------- CSR fill ----------------
__global__ void fill_kernel(const int* __restrict__ src, const int* __restrict__ dst, int E,
                            const int* __restrict__ rp, int* __restrict__ cur, int* __restrict__ csr)
{
    int i = blockIdx.x * blockDim.x + threadIdx.x;
    int stride = gridDim.x * blockDim.x;
    for (; i < E; i += stride) {
        int d = dst[i];
        int pos = rp[d] + atomicAdd(&cur[d], 1);
        csr[pos] = src[i];
    }
}

// ---------------- elementwise add (weight/bias sums) ----------------
__global__ void add2_kernel(const float* __restrict__ a, const float* __restrict__ b,
                            float* __restrict__ o, int n) {
    int i = blockIdx.x * blockDim.x + threadIdx.x;
    if (i < n) o[i] = a[i] + b[i];
}

// ---------------- f32 -> bf16 conversion (4 elems/thread) ----------------
__global__ void cvt_kernel(const float* __restrict__ x, ushort* __restrict__ o, int n4) {
    int i = blockIdx.x * blockDim.x + threadIdx.x;
    if (i >= n4) return;
    float4 v = ((const float4*)x)[i];
    ushort4 r;
    r.x = f2bf(v.x); r.y = f2bf(v.y); r.z = f2bf(v.z); r.w = f2bf(v.w);
    ((ushort4*)o)[i] = r;
}

// ---------------- graph boundaries via binary search (batch is sorted) ----------------
__global__ void bounds_kernel(const int* __restrict__ bu, int nu,
                              const int* __restrict__ bd, int nd,
                              int* __restrict__ bndu, int* __restrict__ bndd)
{
    const int* b = blockIdx.x == 0 ? bu : bd;
    int        n = blockIdx.x == 0 ? nu : nd;
    int*       o = blockIdx.x == 0 ? bndu : bndd;
    int g = threadIdx.x;
    if (g > NG) return;
    int lo = 0, hi = n;
    while (lo < hi) { int m = (lo + hi) >> 1; if (b[m] < g) lo = m + 1; else hi = m; }
    o[g] = lo;
}

// ---------------- CSR mean aggregation: bf16 gather -> bf16 mean rows ----------------
// one wave per dst row; lane covers 2 columns; 8 outstanding gathers
__global__ __launch_bounds__(256) void agg_kernel(
    const ushort* __restrict__ xb,   // [Nsrc,128] bf16
    const int* __restrict__ rp, const int* __restrict__ csr, int M,
    ushort* __restrict__ mean /* [M,128] bf16 */)
{
    int wave = threadIdx.x >> 6, lane = threadIdx.x & 63;
    int row = blockIdx.x * 4 + wave;
    if (row >= M) return;
    int s0 = rp[row], s1 = rp[row + 1];
    float ax = 0.f, ay = 0.f;
    int j = s0;
    for (; j + 8 <= s1; j += 8) {
        unsigned int v0 = *(const unsigned int*)&xb[(size_t)csr[j + 0] * 128 + lane * 2];
        unsigned int v1 = *(const unsigned int*)&xb[(size_t)csr[j + 1] * 128 + lane * 2];
        unsigned int v2 = *(const unsigned int*)&xb[(size_t)csr[j + 2] * 128 + lane * 2];
        unsigned int v3 = *(const unsigned int*)&xb[(size_t)csr[j + 3] * 128 + lane * 2];
        unsigned int v4 = *(const unsigned int*)&xb[(size_t)csr[j + 4] * 128 + lane * 2];
        unsigned int v5 = *(const unsigned int*)&xb[(size_t)csr[j + 5] * 128 + lane * 2];
        unsigned int v6 = *(const unsigned int*)&xb[(size_t)csr[j + 6] * 128 + lane * 2];
        unsigned int v7 = *(const unsigned int*)&xb[(size_t)csr[j + 7] * 128 + lane * 2];
        ax += __uint_as_float(v0 << 16) + __uint_as_float(v1 << 16)
            + __uint_as_float(v2 << 16) + __uint_as_float(v3 << 16)
            + __uint_as_float(v4 << 16) + __uint_as_float(v5 << 16)
            + __uint_as_float(v6 << 16) + __uint_as_float(v7 << 16);
        ay += __uint_as_float(v0 & 0xffff0000u) + __uint_as_float(v1 & 0xffff0000u)
            + __uint_as_float(v2 & 0xffff0000u) + __uint_as_float(v3 & 0xffff0000u)
            + __uint_as_float(v4 & 0xffff0000u) + __uint_as_float(v5 & 0xffff0000u)
            + __uint_as_float(v6 & 0xffff0000u) + __uint_as_float(v7 & 0xffff0000u);
    }
    for (; j < s1; ++j) {
        unsigned int v = *(const unsigned int*)&xb[(size_t)csr[j] * 128 + lane * 2];
        ax += __uint_as_float(v << 16);
        ay += __uint_as_float(v & 0xffff0000u);
    }
    int deg = s1 - s0;
    float sc = 1.f / (float)(deg > 1 ? deg : 1);
    unsigned int pk = (unsigned int)f2bf(ax * sc) | ((unsigned int)f2bf(ay * sc) << 16);
    *(unsigned int*)&mean[(size_t)row * 128 + lane * 2] = pk;
}

// ---------------- dense [M,128]@[128,128] GEMM; A is f32 (AMODE=0) or bf16 (AMODE=1) ----------------
template<int AMODE, bool ACC, bool BIAS, bool RELU>
__global__ __launch_bounds__(256, 2) void gemm_kernel(
    const float* __restrict__ Af, const ushort* __restrict__ Ab, int M,
    const float* __restrict__ W, const float* __restrict__ bias,
    float* __restrict__ C)
{
    __shared__ float Ws[128 * 128];   // 64 KB
    __shared__ float As[32 * 128];    // 16 KB
    const int t = threadIdx.x;
    const int row0 = blockIdx.x * 32;

    {
        const float4* wg = (const float4*)W;
        float4* wl = (float4*)Ws;
        #pragma unroll
        for (int i = 0; i < 16; ++i) wl[t + 256 * i] = wg[t + 256 * i];
    }
    if (AMODE == 0) {
        #pragma unroll
        for (int i = 0; i < 4; ++i) {
            int f = t + 256 * i;
            int rr = f >> 5, cv = f & 31;
            int rg = row0 + rr;
            float4 v = make_float4(0.f, 0.f, 0.f, 0.f);
            if (rg < M) v = ((const float4*)Af)[(size_t)rg * 32 + cv];
            *((float4*)&As[rr * 128 + cv * 4]) = v;
        }
    } else {
        #pragma unroll
        for (int i = 0; i < 2; ++i) {
            int f = t + 256 * i;          // 512 uint4 = 32 rows x 16
            int rr = f >> 4, c16 = f & 15;
            int rg = row0 + rr;
            uint4 v = make_uint4(0u, 0u, 0u, 0u);
            if (rg < M) v = ((const uint4*)Ab)[(size_t)rg * 16 + c16];
            float* dst = &As[rr * 128 + c16 * 8];
            dst[0] = __uint_as_float(v.x << 16); dst[1] = __uint_as_float(v.x & 0xffff0000u);
            dst[2] = __uint_as_float(v.y << 16); dst[3] = __uint_as_float(v.y & 0xffff0000u);
            dst[4] = __uint_as_float(v.z << 16); dst[5] = __uint_as_float(v.z & 0xffff0000u);
            dst[6] = __uint_as_float(v.w << 16); dst[7] = __uint_as_float(v.w & 0xffff0000u);
        }
    }
    __syncthreads();

    const int tx = t & 31, ty = t >> 5;
    float acc[4][4];
    #pragma unroll
    for (int i = 0; i < 4; ++i) { acc[i][0] = 0.f; acc[i][1] = 0.f; acc[i][2] = 0.f; acc[i][3] = 0.f; }

    #pragma unroll 8
    for (int k = 0; k < 128; ++k) {
        float4 w4 = *((const float4*)&Ws[k * 128 + tx * 4]);
        #pragma unroll
        for (int i = 0; i < 4; ++i) {
            float a = As[(ty * 4 + i) * 128 + k];
            acc[i][0] += a * w4.x;
            acc[i][1] += a * w4.y;
            acc[i][2] += a * w4.z;
            acc[i][3] += a * w4.w;
        }
    }

    float4 bv = make_float4(0.f, 0.f, 0.f, 0.f);
    if (BIAS) bv = *((const float4*)&bias[tx * 4]);
    #pragma unroll
    for (int i = 0; i < 4; ++i) {
        int rg = row0 + ty * 4 + i;
        if (rg >= M) continue;
        float4 res;
        res.x = acc[i][0]; res.y = acc[i][1]; res.z = acc[i][2]; res.w = acc[i][3];
        if (BIAS) { res.x += bv.x; res.y += bv.y; res.z += bv.z; res.w += bv.w; }
        if (ACC) {
            float4 cc = ((const float4*)C)[(size_t)rg * 32 + tx];
            res.x += cc.x; res.y += cc.y; res.z += cc.z; res.w += cc.w;
        }
        if (RELU) {
            res.x = fmaxf(res.x, 0.f); res.y = fmaxf(res.y, 0.f);
            res.z = fmaxf(res.z, 0.f); res.w = fmaxf(res.w, 0.f);
        }
        ((float4*)C)[(size_t)rg * 32 + tx] = res;
    }
}

// ---------------- build C[src][g] += 1/deg[dst], g = batch[dst] ----------------
__global__ void cbuild_kernel(const int* __restrict__ src, const int* __restrict__ dst, int E,
                              const int* __restrict__ deg, const int* __restrict__ batch,
                              float* __restrict__ C)
{
    int i = blockIdx.x * blockDim.x + threadIdx.x;
    int stride = gridDim.x * blockDim.x;
    for (; i < E; i += stride) {
        int d = dst[i];
        int g = batch[d];
        float w = 1.f / (float)deg[d];
        atomicAdd(&C[(size_t)src[i] * NG + g], w);
    }
}

// ---------------- pooled agg = C^T @ X; register accumulate + direct atomics ----------------
template<int NOUT>
__global__ __launch_bounds__(256) void poolgemm_kernel(
    const float* __restrict__ Ca, const float* __restrict__ Cb,
    const float* __restrict__ X, int N,
    float* __restrict__ Pa, float* __restrict__ Pb)
{
    int t = threadIdx.x;
    int c4 = t & 31;              // float4 column group
    int g0 = (t >> 5) * 8;        // 8 graphs per thread
    int rows_per = (N + gridDim.x - 1) / gridDim.x;
    int r0 = blockIdx.x * rows_per;
    int r1 = min(N, r0 + rows_per);
    float4 aa[8], ab[8];
    #pragma unroll
    for (int i = 0; i < 8; ++i) {
        aa[i] = make_float4(0.f, 0.f, 0.f, 0.f);
        if (NOUT == 2) ab[i] = make_float4(0.f, 0.f, 0.f, 0.f);
    }
    for (int r = r0; r < r1; ++r) {
        float4 xv = ((const float4*)X)[(size_t)r * 32 + c4];
        const float* ca = Ca + (size_t)r * NG + g0;
        #pragma unroll
        for (int i = 0; i < 8; ++i) {
            float w = ca[i];
            aa[i].x += w * xv.x; aa[i].y += w * xv.y;
            aa[i].z += w * xv.z; aa[i].w += w * xv.w;
        }
        if (NOUT == 2) {
            const float* cb = Cb + (size_t)r * NG + g0;
            #pragma unroll
            for (int i = 0; i < 8; ++i) {
                float w = cb[i];
                ab[i].x += w * xv.x; ab[i].y += w * xv.y;
                ab[i].z += w * xv.z; ab[i].w += w * xv.w;
            }
        }
    }
    #pragma unroll
    for (int i = 0; i < 8; ++i) {
        int base = (g0 + i) * 128 + c4 * 4;
        atomicAdd(&Pa[base + 0], aa[i].x);
        atomicAdd(&Pa[base + 1], aa[i].y);
        atomicAdd(&Pa[base + 2], aa[i].z);
        atomicAdd(&Pa[base + 3], aa[i].w);
        if (NOUT == 2) {
            atomicAdd(&Pb[base + 0], ab[i].x);
            atomicAdd(&Pb[base + 1], ab[i].y);
            atomicAdd(&Pb[base + 2], ab[i].z);
            atomicAdd(&Pb[base + 3], ab[i].w);
        }
    }
}

// ---------------- per-graph row-sum pool (batch sorted -> contiguous ranges) ----------------
__global__ __launch_bounds__(256) void rowpool_kernel(const float* __restrict__ x,
                                                      const int* __restrict__ bnd,
                                                      float* __restrict__ pool)
{
    int g = blockIdx.x & 63, chunk = blockIdx.x >> 6;
    int lo = bnd[g], hi = bnd[g + 1];
    int col = threadIdx.x & 127, half = threadIdx.x >> 7;
    float s = 0.f;
    for (int r = lo + chunk * 2 + half; r < hi; r += 8) s += x[(size_t)r * 128 + col];
    __shared__ float ls[256];
    ls[threadIdx.x] = s;
    __syncthreads();
    if (half == 0) atomicAdd(&pool[g * 128 + col], ls[col] + ls[128 + col]);
}

// ---------------- final: layer-2 matmuls at graph level + MLP + log_softmax ----------------
__global__ __launch_bounds__(128) void final_kernel(
    const float* __restrict__ pmdu, const float* __restrict__ pmuu, const float* __restrict__ pmud,
    const float* __restrict__ pu1,  const float* __restrict__ pd1,
    const int* __restrict__ bndu, const int* __restrict__ bndd,
    const float* __restrict__ Wl2_du, const float* __restrict__ bl2_du, const float* __restrict__ Wr2_du,
    const float* __restrict__ Wl2_uu, const float* __restrict__ bl2_uu, const float* __restrict__ Wr2_uu,
    const float* __restrict__ Wl2_ud, const float* __restrict__ bl2_ud, const float* __restrict__ Wr2_ud,
    const float* __restrict__ W1, const float* __restrict__ b1,
    const float* __restrict__ W2, const float* __restrict__ b2,
    float* __restrict__ out)
{
    int g = blockIdx.x, t = threadIdx.x;
    __shared__ float smdu[128], smuu[128], smud[128], su1[128], sd1[128];
    __shared__ float xrow[256], h[128], lg[2];
    smdu[t] = pmdu[g * 128 + t];
    smuu[t] = pmuu[g * 128 + t];
    smud[t] = pmud[g * 128 + t];
    su1[t]  = pu1[g * 128 + t];
    sd1[t]  = pd1[g * 128 + t];
    __syncthreads();
    float ncu = (float)(bndu[g + 1] - bndu[g]);
    float ncd = (float)(bndd[g + 1] - bndd[g]);
    float cu = ncu > 1.f ? ncu : 1.f, cd = ncd > 1.f ? ncd : 1.f;
    float accu = ncu * (bl2_du[t] + bl2_uu[t]);
    float accd = ncd * bl2_ud[t];
    for (int k = 0; k < 128; ++k) {
        accu += smdu[k] * Wl2_du[k * 128 + t]
              + smuu[k] * Wl2_uu[k * 128 + t]
              + su1[k]  * (Wr2_du[k * 128 + t] + Wr2_uu[k * 128 + t]);
        accd += smud[k] * Wl2_ud[k * 128 + t]
              + sd1[k]  * Wr2_ud[k * 128 + t];
    }
    xrow[t]       = accu / cu;
    xrow[128 + t] = accd / cd;
    __syncthreads();
    float hh = b1[t];
    for (int k = 0; k < 256; ++k) hh += xrow[k] * W1[k * 128 + t];
    h[t] = fmaxf(hh, 0.f);
    __syncthreads();
    if (t < 2) {
        float l = b2[t];
        for (int k = 0; k < 128; ++k) l += h[k] * W2[k * 2 + t];
        lg[t] = l;
    }
    __syncthreads();
    if (t == 0) {
        float m = fmaxf(lg[0], lg[1]);
        float lse = m + logf(expf(lg[0] - m) + expf(lg[1] - m));
        out[g * 2 + 0] = lg[0] - lse;
        out[g * 2 + 1] = lg[1] - lse;
    }
}

extern "C" void kernel_launch(void* const* d_in, const int* in_sizes, int n_in,
                              void* d_out, int out_size, void* d_ws, size_t ws_size,
                              hipStream_t stream)
{
    const float* x_user = (const float*)d_in[0];
    const float* x_drug = (const float*)d_in[1];
    const int* ei_ud = (const int*)d_in[2];
    const int* ei_du = (const int*)d_in[3];
    const int* ei_uu = (const int*)d_in[4];
    const int* batch_u = (const int*)d_in[5];
    const int* batch_d = (const int*)d_in[6];
    const float* Wl1_ud = (const float*)d_in[7];  const float* bl1_ud = (const float*)d_in[8];  const float* Wr1_ud = (const float*)d_in[9];
    const float* Wl1_du = (const float*)d_in[10]; const float* bl1_du = (const float*)d_in[11]; const float* Wr1_du = (const float*)d_in[12];
    const float* Wl1_uu = (const float*)d_in[13]; const float* bl1_uu = (const float*)d_in[14]; const float* Wr1_uu = (const float*)d_in[15];
    const float* Wl2_ud = (const float*)d_in[16]; const float* bl2_ud = (const float*)d_in[17]; const float* Wr2_ud = (const float*)d_in[18];
    const float* Wl2_du = (const float*)d_in[19]; const float* bl2_du = (const float*)d_in[20]; const float* Wr2_du = (const float*)d_in[21];
    const float* Wl2_uu = (const float*)d_in[22]; const float* bl2_uu = (const float*)d_in[23]; const float* Wr2_uu = (const float*)d_in[24];
    const float* W1 = (const float*)d_in[25]; const float* b1 = (const float*)d_in[26];
    const float* W2 = (const float*)d_in[27]; const float* b2 = (const float*)d_in[28];
    (void)n_in; (void)out_size; (void)ws_size;

    const int Nu = in_sizes[0] / 128;
    const int Nd = in_sizes[1] / 128;
    const int E_ud = in_sizes[2] / 2;
    const int E_du = in_sizes[3] / 2;
    const int E_uu = in_sizes[4] / 2;

    char* ws = (char*)d_ws;
    size_t off = 0;
    auto alloc = [&](size_t bytes) -> void* {
        void* p = ws + off;
        off = (off + bytes + 255) & ~(size_t)255;
        return p;
    };
    int* csr_ud = (int*)alloc((size_t)E_ud * 4);
    int* csr_du = (int*)alloc((size_t)E_du * 4);
    int* csr_uu = (int*)alloc((size_t)E_uu * 4);
    int* rp_ud = (int*)alloc((size_t)(Nd + 1) * 4);
    int* rp_du = (int*)alloc((size_t)(Nu + 1) * 4);
    int* rp_uu = (int*)alloc((size_t)(Nu + 1) * 4);
    int* deg_ud = (int*)alloc((size_t)Nd * 4);
    int* deg_du = (int*)alloc((size_t)Nu * 4);
    int* deg_uu = (int*)alloc((size_t)Nu * 4);
    int* cur    = (int*)alloc((size_t)(Nu > Nd ? Nu : Nd) * 4);
    ushort* xb_u = (ushort*)alloc((size_t)Nu * 128 * 2);
    ushort* xb_d = (ushort*)alloc((size_t)Nd * 128 * 2);
    // mean buffers (bf16) — dead after layer-1 GEMMs; C matrices (f32) overlay them 1:1
    ushort* mean_du = (ushort*)alloc((size_t)Nu * 128 * 2);   // src=drug
    ushort* mean_uu = (ushort*)alloc((size_t)Nu * 128 * 2);   // src=user
    ushort* mean_ud = (ushort*)alloc((size_t)Nd * 128 * 2);   // src=user
    float* u1 = (float*)alloc((size_t)Nu * 128 * 4);
    float* d1 = (float*)alloc((size_t)Nd * 128 * 4);
    float* pmdu = (float*)alloc(NG * 128 * 4);
    float* pmuu = (float*)alloc(NG * 128 * 4);
    float* pmud = (float*)alloc(NG * 128 * 4);
    float* pu1  = (float*)alloc(NG * 128 * 4);
    float* pd1  = (float*)alloc(NG * 128 * 4);
    int* bnd_u = (int*)alloc((NG + 1) * 4);
    int* bnd_d = (int*)alloc((NG + 1) * 4);
    float* Wr1s_u = (float*)alloc(128 * 128 * 4);
    float* b1s_u  = (float*)alloc(128 * 4);

    float* C_du = (float*)mean_du;   // [Nd,64] f32 overlays [*,128] bf16 (same bytes)
    float* C_uu = (float*)mean_uu;   // [Nu,64]
    float* C_ud = (float*)mean_ud;   // [Nu,64]

    const int* dst_ud = ei_ud + E_ud;
    const int* dst_du = ei_du + E_du;
    const int* dst_uu = ei_uu + E_uu;

    // ---- CSR build ----
    hipMemsetAsync(deg_ud, 0, (size_t)Nd * 4, stream);
    hipMemsetAsync(deg_du, 0, (size_t)Nu * 4, stream);
    hipMemsetAsync(deg_uu, 0, (size_t)Nu * 4, stream);
    hist_kernel<<<2048, 256, 0, stream>>>(dst_ud, E_ud, deg_ud);
    hist_kernel<<<2048, 256, 0, stream>>>(dst_du, E_du, deg_du);
    hist_kernel<<<2048, 256, 0, stream>>>(dst_uu, E_uu, deg_uu);
    scan3_kernel<<<3, 1024, 0, stream>>>(deg_ud, rp_ud, Nd, deg_du, rp_du, Nu, deg_uu, rp_uu, Nu);
    hipMemsetAsync(cur, 0, (size_t)Nd * 4, stream);
    fill_kernel<<<2048, 256, 0, stream>>>(ei_ud, dst_ud, E_ud, rp_ud, cur, csr_ud);
    hipMemsetAsync(cur, 0, (size_t)Nu * 4, stream);
    fill_kernel<<<2048, 256, 0, stream>>>(ei_du, dst_du, E_du, rp_du, cur, csr_du);
    hipMemsetAsync(cur, 0, (size_t)Nu * 4, stream);
    fill_kernel<<<2048, 256, 0, stream>>>(ei_uu, dst_uu, E_uu, rp_uu, cur, csr_uu);

    // ---- graph boundaries, bf16 inputs, weight sums ----
    bounds_kernel<<<2, NG + 1, 0, stream>>>(batch_u, Nu, batch_d, Nd, bnd_u, bnd_d);
    cvt_kernel<<<(Nu * 32 + 255) / 256, 256, 0, stream>>>(x_user, xb_u, Nu * 32);
    cvt_kernel<<<(Nd * 32 + 255) / 256, 256, 0, stream>>>(x_drug, xb_d, Nd * 32);
    add2_kernel<<<64, 256, 0, stream>>>(Wr1_du, Wr1_uu, Wr1s_u, 128 * 128);
    add2_kernel<<<1, 128, 0, stream>>>(bl1_du, bl1_uu, b1s_u, 128);

    // ---- layer-1 aggregation: high-occupancy bf16 gather means ----
    agg_kernel<<<(Nu + 3) / 4, 256, 0, stream>>>(xb_d, rp_du, csr_du, Nu, mean_du);
    agg_kernel<<<(Nu + 3) / 4, 256, 0, stream>>>(xb_u, rp_uu, csr_uu, Nu, mean_uu);
    agg_kernel<<<(Nd + 3) / 4, 256, 0, stream>>>(xb_u, rp_ud, csr_ud, Nd, mean_ud);

    // ---- layer-1 dense GEMMs ----
    int gBu = (Nu + 31) / 32, gBd = (Nd + 31) / 32;
    gemm_kernel<0, false, true,  false><<<gBu, 256, 0, stream>>>(x_user, nullptr, Nu, Wr1s_u, b1s_u, u1);
    gemm_kernel<1, true,  false, false><<<gBu, 256, 0, stream>>>(nullptr, mean_du, Nu, Wl1_du, nullptr, u1);
    gemm_kernel<1, true,  false, true ><<<gBu, 256, 0, stream>>>(nullptr, mean_uu, Nu, Wl1_uu, nullptr, u1);
    gemm_kernel<0, false, true,  false><<<gBd, 256, 0, stream>>>(x_drug, nullptr, Nd, Wr1_ud, bl1_ud, d1);
    gemm_kernel<1, true,  false, true ><<<gBd, 256, 0, stream>>>(nullptr, mean_ud, Nd, Wl1_ud, nullptr, d1);

    // ---- layer 2: pooled aggregation as C^T @ x1 (C overlays means, now dead) ----
    hipMemsetAsync(C_du, 0, (size_t)Nd * NG * 4, stream);
    hipMemsetAsync(C_uu, 0, (size_t)Nu * NG * 4, stream);
    hipMemsetAsync(C_ud, 0, (size_t)Nu * NG * 4, stream);
    cbuild_kernel<<<2048, 256, 0, stream>>>(ei_du, dst_du, E_du, deg_du, batch_u, C_du);
    cbuild_kernel<<<2048, 256, 0, stream>>>(ei_uu, dst_uu, E_uu, deg_uu, batch_u, C_uu);
    cbuild_kernel<<<2048, 256, 0, stream>>>(ei_ud, dst_ud, E_ud, deg_ud, batch_d, C_ud);

    hipMemsetAsync(pmdu, 0, NG * 128 * 4, stream);
    hipMemsetAsync(pmuu, 0, NG * 128 * 4, stream);
    hipMemsetAsync(pmud, 0, NG * 128 * 4, stream);
    poolgemm_kernel<1><<<512, 256, 0, stream>>>(C_du, nullptr, d1, Nd, pmdu, nullptr);
    poolgemm_kernel<2><<<512, 256, 0, stream>>>(C_uu, C_ud, u1, Nu, pmuu, pmud);

    // ---- root-term pools ----
    hipMemsetAsync(pu1, 0, NG * 128 * 4, stream);
    hipMemsetAsync(pd1, 0, NG * 128 * 4, stream);
    rowpool_kernel<<<NG * 4, 256, 0, stream>>>(u1, bnd_u, pu1);
    rowpool_kernel<<<NG * 4, 256, 0, stream>>>(d1, bnd_d, pd1);

    // ---- graph-level layer-2 matmuls + MLP + log_softmax ----
    final_kernel<<<NG, 128, 0, stream>>>(pmdu, pmuu, pmud, pu1, pd1, bnd_u, bnd_d,
                                         Wl2_du, bl2_du, Wr2_du,
                                         Wl2_uu, bl2_uu, Wr2_uu,
                                         Wl2_ud, bl2_ud, Wr2_ud,
                                         W1, b1, W2, b2, (float*)d_out);
}